// Round 17
// 865.564 us; speedup vs baseline: 1.5356x; 1.1097x over previous
//
#include <hip/hip_runtime.h>
#include <hip/hip_bf16.h>

// ---------------------------------------------------------------------------
// M3Care forward — bf16 MFMA GEMMs (global_load_lds staging + XCD swizzle +
// bf16 split-K + z-batched small GEMMs + thin-tile GEMMs incl. row-major
// fused QKV), fused dist+gk+sim (z=3 parallel bf16 planes, thin tile, 1-exp
// gk3), z-batched weight transposes, PE table, MFMA attention with in-LDS
// V-transpose, closed-form bandwidth, batched BN. N=2048, D=256, NE=34.
// ---------------------------------------------------------------------------

#define NN 2048
#define DD 256
#define LTOK 34

typedef __attribute__((ext_vector_type(8))) short bf16x8;
typedef __attribute__((ext_vector_type(4))) float f32x4;

__device__ __forceinline__ float bf2f(__hip_bfloat16 x) { return __bfloat162float(x); }
__device__ __forceinline__ __hip_bfloat16 f2bf(float x) { return __float2bfloat16(x); }
__device__ __forceinline__ float us2f(ushort u) {
    unsigned x = (unsigned)u << 16;
    float f;
    __builtin_memcpy(&f, &x, 4);
    return f;
}
__device__ __forceinline__ ushort f2us(float x) {
    __hip_bfloat16 h = f2bf(x);
    ushort u;
    __builtin_memcpy(&u, &h, 2);
    return u;
}

// ---------------- block reduce (blockDim.x == 256) ----------------
__device__ __forceinline__ float block_reduce_sum256(float v, float* red) {
    for (int o = 32; o > 0; o >>= 1) v += __shfl_down(v, o, 64);
    int tid = threadIdx.x;
    if ((tid & 63) == 0) red[tid >> 6] = v;
    __syncthreads();
    float s = red[0] + red[1] + red[2] + red[3];
    __syncthreads();
    return s;
}

// XCD-chunked bijective remap (T1, m204 variant).
__device__ __forceinline__ int xcd_remap(int lin, int nwg) {
    int q = nwg >> 3, r = nwg & 7;
    int xcd = lin & 7, pos = lin >> 3;
    return (xcd < r ? xcd * (q + 1) : r * (q + 1) + (xcd - r) * q) + pos;
}

// Stage one 128x64 bf16 tile via global_load_lds (16B/lane), linear LDS dest,
// inverse-XOR-swizzled per-lane GLOBAL source (rule #21).
__device__ __forceinline__ void stage_tile(const ushort* __restrict__ src,
                                           ushort* lds, int grow0, size_t ldk,
                                           int k0, int wv, int l) {
#pragma unroll
    for (int c = 0; c < 4; ++c) {
        int rowbase = wv * 32 + c * 8;
        int row = rowbase + (l >> 3);
        int sx = ((l & 7) ^ (row & 7)) * 8;
        __builtin_amdgcn_global_load_lds(
            (const __attribute__((address_space(1))) void*)(src + (size_t)(grow0 + row) * ldk + k0 + sx),
            (__attribute__((address_space(3))) void*)(lds + rowbase * 64), 16, 0, 0);
    }
}

// 64-row variant (A-tile of the thin GEMM)
__device__ __forceinline__ void stage_tile64(const ushort* __restrict__ src,
                                             ushort* lds, int grow0, size_t ldk,
                                             int k0, int wv, int l) {
#pragma unroll
    for (int c = 0; c < 2; ++c) {
        int rowbase = wv * 16 + c * 8;
        int row = rowbase + (l >> 3);
        int sx = ((l & 7) ^ (row & 7)) * 8;
        __builtin_amdgcn_global_load_lds(
            (const __attribute__((address_space(1))) void*)(src + (size_t)(grow0 + row) * ldk + k0 + sx),
            (__attribute__((address_space(3))) void*)(lds + rowbase * 64), 16, 0, 0);
    }
}

// MFMA inner step over the staged 128x64 tiles (one kk half)
#define MFMA_STEP(ACC)                                                          \
    {                                                                           \
        bf16x8 av[4], bv[4];                                                    \
        _Pragma("unroll") for (int f = 0; f < 4; ++f) {                         \
            int ra = wr * 64 + f * 16 + lr;                                     \
            av[f] = *(const bf16x8*)(As + ra * 64 + (((kk * 4 + l16) ^ (ra & 7)) * 8)); \
            int rb = wc * 64 + f * 16 + lr;                                     \
            bv[f] = *(const bf16x8*)(Bs + rb * 64 + (((kk * 4 + l16) ^ (rb & 7)) * 8)); \
        }                                                                       \
        _Pragma("unroll") for (int mf = 0; mf < 4; ++mf)                        \
            _Pragma("unroll") for (int nf = 0; nf < 4; ++nf)                    \
                ACC[mf][nf] = __builtin_amdgcn_mfma_f32_16x16x32_bf16(          \
                    av[mf], bv[nf], ACC[mf][nf], 0, 0, 0);                      \
    }

// Thin-tile (64-row A) MFMA inner step
#define MFMA_STEP_T(ACC)                                                        \
    {                                                                           \
        bf16x8 av[2], bv[4];                                                    \
        _Pragma("unroll") for (int f = 0; f < 2; ++f) {                         \
            int ra = wr * 32 + f * 16 + lr;                                     \
            av[f] = *(const bf16x8*)(As + ra * 64 + (((kk * 4 + l16) ^ (ra & 7)) * 8)); \
        }                                                                       \
        _Pragma("unroll") for (int f = 0; f < 4; ++f) {                         \
            int rb = wc * 64 + f * 16 + lr;                                     \
            bv[f] = *(const bf16x8*)(Bs + rb * 64 + (((kk * 4 + l16) ^ (rb & 7)) * 8)); \
        }                                                                       \
        _Pragma("unroll") for (int mf = 0; mf < 2; ++mf)                        \
            _Pragma("unroll") for (int nf = 0; nf < 4; ++nf)                    \
                ACC[mf][nf] = __builtin_amdgcn_mfma_f32_16x16x32_bf16(          \
                    av[mf], bv[nf], ACC[mf][nf], 0, 0, 0);                      \
    }

// ---------------------------------------------------------------------------
// bf16 MFMA GEMM (big/split-K): C[M,N] = A[M,K] @ Bt[N,K]^T (+bias)
// OUTM: 0 = f32 out (slice z*M*N), 1 = bf16 out, 3 = bf16 in-place add,
//       5 = bf16 split-K slice out.
// ---------------------------------------------------------------------------
template <int OUTM, bool BIAS, bool RELU>
__global__ __launch_bounds__(256) void gemm_mfma(
    const ushort* __restrict__ A, const ushort* __restrict__ Bt,
    const float* __restrict__ bias, void* __restrict__ Cout,
    int M, int N, int K)
{
    __shared__ __align__(16) ushort As[128 * 64];
    __shared__ __align__(16) ushort Bs[128 * 64];
    const int gx = gridDim.x;
    int lin = xcd_remap(blockIdx.y * gx + blockIdx.x, gx * gridDim.y);
    const int bm = (lin / gx) * 128, bn = (lin % gx) * 128;
    const int tid = threadIdx.x;
    const int l = tid & 63, wv = tid >> 6;
    const int wr = wv >> 1, wc = wv & 1;
    const int l16 = l >> 4, lr = l & 15;
    const int kpz = K / gridDim.z;
    const int kbeg = blockIdx.z * kpz, kend = kbeg + kpz;
    f32x4 zero = {0.f, 0.f, 0.f, 0.f};
    f32x4 acc[4][4];
#pragma unroll
    for (int i = 0; i < 4; ++i)
#pragma unroll
        for (int j = 0; j < 4; ++j) acc[i][j] = zero;

    for (int k0 = kbeg; k0 < kend; k0 += 64) {
        stage_tile(A, As, bm, K, k0, wv, l);
        stage_tile(Bt, Bs, bn, K, k0, wv, l);
        __syncthreads();
#pragma unroll
        for (int kk = 0; kk < 2; ++kk) MFMA_STEP(acc)
        __syncthreads();
    }
    float* Cf = (float*)Cout + (size_t)blockIdx.z * M * N;
    __hip_bfloat16* Cb = (__hip_bfloat16*)Cout + (size_t)blockIdx.z * M * N;
#pragma unroll
    for (int mf = 0; mf < 4; ++mf) {
#pragma unroll
        for (int nf = 0; nf < 4; ++nf) {
            int col = bn + wc * 64 + nf * 16 + lr;
            float bb = BIAS ? bias[col] : 0.f;
#pragma unroll
            for (int r = 0; r < 4; ++r) {
                int row = bm + wr * 64 + mf * 16 + l16 * 4 + r;
                float v = acc[mf][nf][r] + bb;
                if (OUTM == 3)
                    v += bf2f(((const __hip_bfloat16*)Cout)[(size_t)row * N + col]);
                if (RELU) v = fmaxf(v, 0.f);
                if (OUTM == 0)
                    Cf[(size_t)row * N + col] = v;
                else if (OUTM == 5)
                    Cb[(size_t)row * N + col] = f2bf(v);
                else
                    ((__hip_bfloat16*)Cout)[(size_t)row * N + col] = f2bf(v);
            }
        }
    }
}

// ---------------------------------------------------------------------------
// Thin-tile GEMM: 64x128 tile, 24KB LDS. OUTM: 1 = bf16 out, 3 = add.
// ---------------------------------------------------------------------------
template <int OUTM, bool BIAS, bool RELU>
__global__ __launch_bounds__(256) void gemm_thin(
    const ushort* __restrict__ A, const ushort* __restrict__ Bt,
    const float* __restrict__ bias, void* __restrict__ Cout,
    int M, int N, int K)
{
    __shared__ __align__(16) ushort As[64 * 64];
    __shared__ __align__(16) ushort Bs[128 * 64];
    const int gx = gridDim.x;
    int lin = xcd_remap(blockIdx.y * gx + blockIdx.x, gx * gridDim.y);
    const int bm = (lin / gx) * 64, bn = (lin % gx) * 128;
    const int tid = threadIdx.x;
    const int l = tid & 63, wv = tid >> 6;
    const int wr = wv >> 1, wc = wv & 1;
    const int l16 = l >> 4, lr = l & 15;
    f32x4 zero = {0.f, 0.f, 0.f, 0.f};
    f32x4 acc[2][4];
#pragma unroll
    for (int i = 0; i < 2; ++i)
#pragma unroll
        for (int j = 0; j < 4; ++j) acc[i][j] = zero;

    for (int k0 = 0; k0 < K; k0 += 64) {
        stage_tile64(A, As, bm, K, k0, wv, l);
        stage_tile(Bt, Bs, bn, K, k0, wv, l);
        __syncthreads();
#pragma unroll
        for (int kk = 0; kk < 2; ++kk) MFMA_STEP_T(acc)
        __syncthreads();
    }
#pragma unroll
    for (int mf = 0; mf < 2; ++mf) {
#pragma unroll
        for (int nf = 0; nf < 4; ++nf) {
            int col = bn + wc * 64 + nf * 16 + lr;
            float bb = BIAS ? bias[col] : 0.f;
#pragma unroll
            for (int r = 0; r < 4; ++r) {
                int row = bm + wr * 32 + mf * 16 + l16 * 4 + r;
                float v = acc[mf][nf][r] + bb;
                if (OUTM == 3)
                    v += bf2f(((const __hip_bfloat16*)Cout)[(size_t)row * N + col]);
                if (RELU) v = fmaxf(v, 0.f);
                ((__hip_bfloat16*)Cout)[(size_t)row * N + col] = f2bf(v);
            }
        }
    }
}

// ---------------------------------------------------------------------------
// z-batched small GEMM (K<=256).
// ---------------------------------------------------------------------------
template <int OUTM, bool RELU, bool BIAS, bool PSUM>
__global__ __launch_bounds__(256) void gemm_batch(
    const ushort* __restrict__ A, int lda, size_t aoffZ,
    const ushort* __restrict__ Bt, size_t boffZ,
    const float* __restrict__ bias, int biasoffZ,
    void* __restrict__ Cout, int ldc, size_t coffZ,
    float* __restrict__ psum, int M, int N, int K)
{
    __shared__ __align__(16) ushort As[128 * 64];
    __shared__ __align__(16) ushort Bs[128 * 64];
    __shared__ float red[8];
    const int gx = gridDim.x;
    const int lin0 = blockIdx.y * gx + blockIdx.x;
    int lin = xcd_remap(lin0, gx * gridDim.y);
    const int bm = (lin / gx) * 128, bn = (lin % gx) * 128;
    const int z = blockIdx.z;
    A += (size_t)z * aoffZ;
    Bt += (size_t)z * boffZ;
    if (BIAS) bias += (size_t)z * biasoffZ;
    const int tid = threadIdx.x;
    const int l = tid & 63, wv = tid >> 6;
    const int wr = wv >> 1, wc = wv & 1;
    const int l16 = l >> 4, lr = l & 15;
    f32x4 zero = {0.f, 0.f, 0.f, 0.f};
    f32x4 acc[4][4];
#pragma unroll
    for (int i = 0; i < 4; ++i)
#pragma unroll
        for (int j = 0; j < 4; ++j) acc[i][j] = zero;

    for (int k0 = 0; k0 < K; k0 += 64) {
        stage_tile(A, As, bm, lda, k0, wv, l);
        stage_tile(Bt, Bs, bn, K, k0, wv, l);
        __syncthreads();
#pragma unroll
        for (int kk = 0; kk < 2; ++kk) MFMA_STEP(acc)
        __syncthreads();
    }
    float lsq = 0.f;
#pragma unroll
    for (int mf = 0; mf < 4; ++mf) {
#pragma unroll
        for (int nf = 0; nf < 4; ++nf) {
            int col = bn + wc * 64 + nf * 16 + lr;
            float bb = BIAS ? bias[col] : 0.f;
#pragma unroll
            for (int r = 0; r < 4; ++r) {
                int row = bm + wr * 64 + mf * 16 + l16 * 4 + r;
                float v = acc[mf][nf][r] + bb;
                if (RELU) v = fmaxf(v, 0.f);
                if (PSUM) lsq += v * v;
                if (OUTM == 0)
                    ((float*)Cout + (size_t)z * coffZ)[(size_t)row * ldc + col] = v;
                else if (OUTM == 2)
                    ((__hip_bfloat16*)Cout + (size_t)z * coffZ)[(size_t)col * M + row] = f2bf(v);
                else
                    ((__hip_bfloat16*)Cout + (size_t)z * coffZ)[(size_t)row * ldc + col] = f2bf(v);
            }
        }
    }
    if (PSUM) {
        float bs = block_reduce_sum256(lsq, red);
        if (tid == 0) psum[z * gx * gridDim.y + lin0] = bs;
    }
}

// ---------------------------------------------------------------------------
// Fused dual-distance + multi-bandwidth GK, z = modal (parallel bf16 planes),
// THIN 64x128 tile. gk3(d) = t + t^2 + t^4, ONE exp per plane. Grid(16,32,3).
// ---------------------------------------------------------------------------
__global__ __launch_bounds__(256) void gemm_dist_gk3(
    const ushort* __restrict__ XB6, const float* __restrict__ SQ6,
    const float* __restrict__ bws, const int* __restrict__ MK,
    const float* __restrict__ epsp, ushort* __restrict__ S3b)
{
    __shared__ __align__(16) ushort As[64 * 64];
    __shared__ __align__(16) ushort Bs[128 * 64];
    const int gx = gridDim.x;
    int lin = xcd_remap(blockIdx.y * gx + blockIdx.x, gx * gridDim.y);
    const int bm = (lin / gx) * 64, bn = (lin % gx) * 128;
    const int z = blockIdx.z;
    const ushort* XB = XB6 + (size_t)(2 * z) * NN * DD;
    const float* SQ = SQ6 + (size_t)(2 * z) * NN;
    const int* mk = MK + (size_t)z * NN;
    ushort* S = S3b + (size_t)z * NN * NN;
    const int tid = threadIdx.x;
    const int l = tid & 63, wv = tid >> 6;
    const int wr = wv >> 1, wc = wv & 1;
    const int l16 = l >> 4, lr = l & 15;
    f32x4 zero = {0.f, 0.f, 0.f, 0.f};
    f32x4 acc1[2][4], acc2[2][4];
#pragma unroll
    for (int i = 0; i < 2; ++i)
#pragma unroll
        for (int j = 0; j < 4; ++j) { acc1[i][j] = zero; acc2[i][j] = zero; }

    for (int k0 = 0; k0 < 256; k0 += 64) {
        stage_tile64(XB, As, bm, 256, k0, wv, l);
        stage_tile(XB, Bs, bn, 256, k0, wv, l);
        __syncthreads();
#pragma unroll
        for (int kk = 0; kk < 2; ++kk) MFMA_STEP_T(acc1)
        __syncthreads();
    }
    const ushort* X1 = XB + (size_t)NN * DD;
    for (int k0 = 0; k0 < 256; k0 += 64) {
        stage_tile64(X1, As, bm, 256, k0, wv, l);
        stage_tile(X1, Bs, bn, 256, k0, wv, l);
        __syncthreads();
#pragma unroll
        for (int kk = 0; kk < 2; ++kk) MFMA_STEP_T(acc2)
        __syncthreads();
    }
    float eps = 1.f / (1.f + __expf(-epsp[z]));
    const float cnn = 1.f / ((float)NN * NN - (float)NN);
    float ia4 = 0.5f / (bws[2 * z] * cnn);
    float ib4 = 0.5f / (bws[2 * z + 1] * cnn);
#pragma unroll
    for (int mf = 0; mf < 2; ++mf) {
#pragma unroll
        for (int nf = 0; nf < 4; ++nf) {
            int col = bn + wc * 64 + nf * 16 + lr;
            int mcol = mk[col];
            float sqc0 = SQ[col], sqc1 = SQ[NN + col];
#pragma unroll
            for (int r = 0; r < 4; ++r) {
                int row = bm + wr * 32 + mf * 16 + l16 * 4 + r;
                float d1 = fmaxf(SQ[row] + sqc0 - 2.f * acc1[mf][nf][r], 0.f);
                float d2 = fmaxf(SQ[NN + row] + sqc1 - 2.f * acc2[mf][nf][r], 0.f);
                float t = __expf(-d1 * ia4);
                float t2 = t * t;
                float w = t + t2 + t2 * t2;
                float u = __expf(-d2 * ib4);
                float u2 = u * u;
                float g = u + u2 + u2 * u2;
                float val = ((1.f - eps) * w + eps) * g;
                val = (mk[row] && mcol) ? val : 0.f;
                S[(size_t)row * NN + col] = f2us(val);
            }
        }
    }
}

// ---------------- bandwidth, closed form (z = 0..5) ----------------
__global__ __launch_bounds__(256) void bw_fast6(const float* __restrict__ SQ6,
                                                const float* __restrict__ bnb,
                                                float* __restrict__ SCbw) {
    __shared__ float red[8];
    int z = blockIdx.x, tid = threadIdx.x;
    float s1p = 0.f;
    for (int r = tid; r < NN; r += 256) s1p += SQ6[z * NN + r];
    float b = bnb[tid];
    float s1 = block_reduce_sum256(s1p, red);
    float b2 = block_reduce_sum256(b * b, red);
    if (tid == 0)
        SCbw[z] = 2.f * (float)NN * s1 - 2.f * (float)NN * (float)NN * b2;
}

// ---------------- split-K finalize (bf16 slices) ----------------
template <int Z, bool RELU>
__global__ __launch_bounds__(256) void slice_fin_b(const ushort4* __restrict__ SL,
                                                   const float* __restrict__ bias,
                                                   __hip_bfloat16* __restrict__ out,
                                                   int N, size_t MN) {
    size_t v = (size_t)blockIdx.x * 256 + threadIdx.x;
    size_t MN4 = MN >> 2;
    float sx = 0.f, sy = 0.f, sz = 0.f, sw = 0.f;
#pragma unroll
    for (int z = 0; z < Z; ++z) {
        ushort4 t = SL[(size_t)z * MN4 + v];
        sx += us2f(t.x); sy += us2f(t.y); sz += us2f(t.z); sw += us2f(t.w);
    }
    float4 bb = ((const float4*)bias)[v % (size_t)(N >> 2)];
    sx += bb.x; sy += bb.y; sz += bb.z; sw += bb.w;
    if (RELU) {
        sx = fmaxf(sx, 0.f); sy = fmaxf(sy, 0.f);
        sz = fmaxf(sz, 0.f); sw = fmaxf(sw, 0.f);
    }
    union { __hip_bfloat16 h[4]; ushort4 u; } pk;
    pk.h[0] = f2bf(sx); pk.h[1] = f2bf(sy);
    pk.h[2] = f2bf(sz); pk.h[3] = f2bf(sw);
    ((ushort4*)out)[v] = pk.u;
}

// ---------------- conversions ----------------
__global__ void cvt_flat(const float* __restrict__ in, __hip_bfloat16* __restrict__ out,
                         int n4) {
    int i = blockIdx.x * 256 + threadIdx.x;
    if (i < n4) {
        float4 v = ((const float4*)in)[i];
        union { __hip_bfloat16 h[4]; ushort4 u; } pk;
        pk.h[0] = f2bf(v.x); pk.h[1] = f2bf(v.y);
        pk.h[2] = f2bf(v.z); pk.h[3] = f2bf(v.w);
        ((ushort4*)out)[i] = pk.u;
    }
}

// z-batched f32 [R,C] -> bf16 [C,R] (z slabs of R*C)
__global__ __launch_bounds__(256) void cvt_transz(const float* __restrict__ in,
                                                  __hip_bfloat16* __restrict__ out,
                                                  int R, int C) {
    __shared__ float t[32][33];
    size_t zo = (size_t)blockIdx.z * R * C;
    in += zo;
    out += zo;
    int bc = blockIdx.x * 32, br = blockIdx.y * 32;
    int tx = threadIdx.x & 31, ty = threadIdx.x >> 5;
#pragma unroll
    for (int i = 0; i < 32; i += 8)
        t[ty + i][tx] = in[(size_t)(br + ty + i) * C + bc + tx];
    __syncthreads();
#pragma unroll
    for (int i = 0; i < 32; i += 8)
        out[(size_t)(bc + ty + i) * R + br + tx] = f2bf(t[tx][ty + i]);
}

// ---------------- 3-plane (bf16) aggregation + threshold + cvt ------------
__global__ __launch_bounds__(256) void agg_cvt3(
    const ushort4* __restrict__ S3b, const int* __restrict__ mk0,
    const int* __restrict__ mk1, const int* __restrict__ mk2,
    const float* __restrict__ dissim, ushort4* __restrict__ Sb) {
    size_t v = (size_t)blockIdx.x * 256 + threadIdx.x;
    const size_t PL = (size_t)NN * NN / 4;
    int i = (int)(v >> 9);
    int j0 = (int)((v & 511) << 2);
    float thr = 1.f / (1.f + __expf(-dissim[0]));
    ushort4 u0 = S3b[v], u1 = S3b[PL + v], u2 = S3b[2 * PL + v];
    int m0i = mk0[i], m1i = mk1[i], m2i = mk2[i];
    union { __hip_bfloat16 h[4]; ushort4 u; } pk;
#define AGGC(C0, C1, C2, J)                                                       \
    {                                                                             \
        int j = j0 + J;                                                           \
        int cnt = ((m0i && mk0[j]) ? 1 : 0) + ((m1i && mk1[j]) ? 1 : 0) +         \
                  ((m2i && mk2[j]) ? 1 : 0);                                      \
        float a = cnt ? (us2f(C0) + us2f(C1) + us2f(C2)) / (float)cnt : 0.f;      \
        pk.h[J] = f2bf((a > thr) ? a : 0.f);                                      \
    }
    AGGC(u0.x, u1.x, u2.x, 0) AGGC(u0.y, u1.y, u2.y, 1)
    AGGC(u0.z, u1.z, u2.z, 2) AGGC(u0.w, u1.w, u2.w, 3)
#undef AGGC
    Sb[v] = pk.u;
}

// ---------------- BatchNorm column stats, z = modal*2 + {0:P(relu),1:E} ----
__global__ __launch_bounds__(256) void colstats6(const float* __restrict__ P3,
                                                 const float* __restrict__ E0,
                                                 const float* __restrict__ e1,
                                                 const float* __restrict__ e2,
                                                 float* __restrict__ mv, int nrows) {
    __shared__ float red[8];
    int c = blockIdx.x, z = blockIdx.y, tid = threadIdx.x;
    int m = z >> 1, kind = z & 1;
    const float* X = kind ? (m == 0 ? E0 : (m == 1 ? e1 : e2))
                          : P3 + (size_t)m * NN * DD;
    float s = 0.f, sq = 0.f;
    for (int r = tid; r < nrows; r += 256) {
        float v = X[(size_t)r * DD + c];
        if (!kind) v = fmaxf(v, 0.f);
        s += v; sq += v * v;
    }
    float ts = block_reduce_sum256(s, red);
    float tq = block_reduce_sum256(sq, red);
    if (tid == 0) {
        float mmean = ts / (float)nrows;
        mv[z * 512 + c] = mmean;
        mv[z * 512 + 256 + c] = tq / (float)nrows - mmean * mmean;
    }
}

// ---------------- fused BN-apply + rowsq, z = 0..5 (block = row) ----------
__global__ __launch_bounds__(256) void bn_fuse6(const float* __restrict__ P3,
                                                const float* __restrict__ E0,
                                                const float* __restrict__ e1,
                                                const float* __restrict__ e2,
                                                const float* __restrict__ mv,
                                                const float* __restrict__ g,
                                                const float* __restrict__ b,
                                                ushort* __restrict__ XB6,
                                                float* __restrict__ SQ6) {
    __shared__ float red[8];
    int r = blockIdx.x, z = blockIdx.y, c = threadIdx.x;
    int m = z >> 1, kind = z & 1;
    const float* X = kind ? (m == 0 ? E0 : (m == 1 ? e1 : e2))
                          : P3 + (size_t)m * NN * DD;
    float v = X[(size_t)r * DD + c];
    if (!kind) v = fmaxf(v, 0.f);
    float y = (v - mv[z * 512 + c]) * rsqrtf(mv[z * 512 + 256 + c] + 1e-5f) * g[c] + b[c];
    __hip_bfloat16 yb = f2bf(y);
    XB6[(size_t)z * NN * DD + (size_t)r * DD + c] = *(ushort*)&yb;
    float yr = bf2f(yb);
    float s = block_reduce_sum256(yr * yr, red);
    if (c == 0) SQ6[z * NN + r] = s;
}

// ---------------- sum-of-squares partial ----------------
__global__ __launch_bounds__(256) void sumsq_partial(const float* __restrict__ X, int n,
                                                     float* __restrict__ part) {
    __shared__ float red[8];
    int tid = threadIdx.x;
    float s = 0.f;
    for (size_t idx = (size_t)blockIdx.x * 256 + tid; idx < (size_t)n;
         idx += (size_t)gridDim.x * 256) {
        float v = X[idx];
        s += v * v;
    }
    float bs = block_reduce_sum256(s, red);
    if (tid == 0) part[blockIdx.x] = bs;
}

__global__ __launch_bounds__(256) void reduce6(const float* __restrict__ part,
                                               float* __restrict__ SC) {
    __shared__ float red[8];
    int b = blockIdx.x, tid = threadIdx.x;
    const float* src; int n, dst;
    if (b < 3) { src = part + 512 + b * 512; n = 512; dst = 9 + b; }
    else { src = part + 2048 + (b - 3) * 32; n = 32; dst = 6 + (b - 3); }
    float s = 0.f;
    for (int i = tid; i < n; i += 256) s += src[i];
    float bs = block_reduce_sum256(s, red);
    if (tid == 0) SC[dst] = bs;
}

// ---------------- adapt-gate imputation ----------------
__global__ __launch_bounds__(256) void impute_k(
    const float* __restrict__ E, const __hip_bfloat16* __restrict__ H, int ldh,
    const float* __restrict__ aw, const float* __restrict__ ab,
    const int* __restrict__ mk, float* __restrict__ OUT) {
    __shared__ float red[8];
    int i = blockIdx.x, tid = threadIdx.x;
    float e = E[(size_t)i * DD + tid], h = bf2f(H[(size_t)i * ldh + tid]), w = aw[tid];
    float se = block_reduce_sum256(e * w, red);
    float sh = block_reduce_sum256(h * w, red);
    float s = 1.f / (1.f + __expf(-(se + ab[0])));
    float o = 1.f / (1.f + __expf(-(sh + ab[0])));
    s = s / (s + o);
    float imp = s * e + (1.f - s) * h;
    float m = mk[i] ? 1.f : 0.f;
    OUT[(size_t)i * DD + tid] = imp * m + (1.f - m) * h;
}

// ---------------- masks ----------------
__global__ void detect_mode(const void* __restrict__ m1, int* __restrict__ modep) {
    if (threadIdx.x == 0 && blockIdx.x == 0) {
        int vi = ((const int*)m1)[0];
        float vf = ((const float*)m1)[0];
        modep[0] = (vi == 1) ? 0 : ((vf == 1.0f) ? 2 : 1);
    }
}

__device__ __forceinline__ int rd_mask(const void* p, int idx, int mode) {
    if (mode == 0) return ((const int*)p)[idx] != 0;
    if (mode == 1) return ((const unsigned char*)p)[idx] != 0;
    return ((const float*)p)[idx] != 0.f;
}

__global__ void build_masks(const void* __restrict__ m0, const void* __restrict__ m1,
                            const void* __restrict__ m2, const int* __restrict__ modep,
                            int* __restrict__ MK, int* __restrict__ TOK) {
    int mode = modep[0];
    int idx = blockIdx.x * 256 + threadIdx.x;
    if (idx < NN) {
        MK[idx] = rd_mask(m0, idx * 32, mode);
        MK[NN + idx] = rd_mask(m1, idx, mode);
        MK[2 * NN + idx] = rd_mask(m2, idx, mode);
    }
    if (idx < NN * LTOK) {
        int i = idx / LTOK, t = idx - i * LTOK;
        TOK[idx] = (t < 32) ? rd_mask(m0, i * 32 + t, mode)
                            : ((t == 32) ? rd_mask(m1, i, mode) : rd_mask(m2, i, mode));
    }
}

// ---------------- gather emb0[:,0,:] ----------------
__global__ void gather_e0(const float* __restrict__ emb0, float* __restrict__ E0,
                          __hip_bfloat16* __restrict__ E0b) {
    int i = blockIdx.x, c = threadIdx.x;
    float v = emb0[(size_t)i * 32 * DD + c];
    E0[(size_t)i * DD + c] = v;
    E0b[(size_t)i * DD + c] = f2bf(v);
}

// ---------------- PE + type_emb[0] table ----------------
__global__ void pe_table(const float* __restrict__ type_emb, float* __restrict__ PET) {
    int t = blockIdx.x, c = threadIdx.x;
    float div = __expf((float)((c >> 1) << 1) * (-9.210340371976184f / 256.f));
    float ang = (float)t * div;
    float pe = (c & 1) ? __cosf(ang) : __sinf(ang);
    PET[t * 256 + c] = type_emb[c] + pe;
}

// ---------------- build token sequence ----------------
__global__ void build_z2(const float4* __restrict__ emb0, const float4* __restrict__ i0,
                         const float4* __restrict__ i1, const float4* __restrict__ i2,
                         const float4* __restrict__ PET,
                         const float4* __restrict__ type_emb,
                         ushort4* __restrict__ Z) {
    int idx = blockIdx.x * 256 + threadIdx.x;
    int c4 = idx & 63;
    int t = (idx >> 6) % LTOK;
    int i = idx / (LTOK * 64);
    float4 v, a;
    if (t < 32) {
        v = (t == 0) ? i0[(size_t)i * 64 + c4]
                     : emb0[((size_t)i * 32 + t) * 64 + c4];
        a = PET[t * 64 + c4];
    } else if (t == 32) {
        v = i1[(size_t)i * 64 + c4];
        a = type_emb[64 + c4];
    } else {
        v = i2[(size_t)i * 64 + c4];
        a = type_emb[128 + c4];
    }
    union { __hip_bfloat16 h[4]; ushort4 u; } pk;
    pk.h[0] = f2bf(v.x + a.x); pk.h[1] = f2bf(v.y + a.y);
    pk.h[2] = f2bf(v.z + a.z); pk.h[3] = f2bf(v.w + a.w);
    Z[idx] = pk.u;
}

// ---------------------------------------------------------------------------
// MFMA attention with in-LDS V-transpose. 1 sample/block, 4 waves.
// QKV row-major [rows][768] (Q|K|V). V is staged to VT_lds[256][42]
// (stride 42 = 21 dwords, gcd(21,32)=1 -> conflict-free both ways);
// j in [34,42) zeroed so cross-row bf16x8 reads multiply P-zeros.
// ---------------------------------------------------------------------------
template <int DH, int NH>
__global__ __launch_bounds__(256) void attn_mfma(
    const ushort* __restrict__ QKV, const int* __restrict__ tok,
    __hip_bfloat16* __restrict__ O, int sample0)
{
    __shared__ float S_lds[48][49];
    __shared__ ushort P_lds[48][72];
    __shared__ __align__(16) ushort VT_lds[256 * 42 + 64];
    __shared__ int tok_lds[34];
    const int s = blockIdx.x;
    const int tid = threadIdx.x;
    const int wv = tid >> 6, l = tid & 63, lr = l & 15, l16 = l >> 4;
    const int rowQ = s * 34;
    if (tid < 34) tok_lds[tid] = tok[(size_t)(sample0 + s) * LTOK + tid];
    // zero the j-pad region [34,42) of all 256 d-rows (+ tail guard)
    for (int idx = tid; idx < 256 * 8 + 64; idx += 256) {
        int d = idx >> 3, jp = 34 + (idx & 7);
        int off = (idx < 2048) ? d * 42 + jp : 256 * 42 + (idx - 2048);
        VT_lds[off] = 0;
    }
    // stage V transposed: VT_lds[d*42 + j] = V[j][d]; coalesced global read,
    // stride-42 LDS write (21 dwords -> conflict-free)
    for (int idx = tid; idx < 34 * 256; idx += 256) {
        int j = idx >> 8, d = idx & 255;
        VT_lds[d * 42 + j] = QKV[(size_t)(rowQ + j) * 768 + 512 + d];
    }
    const float scale = rsqrtf((float)DH);
    __syncthreads();
#pragma unroll
    for (int h = 0; h < NH; ++h) {
        for (int t = wv; t < 9; t += 4) {
            int mj = t / 3, ni = t % 3;
            f32x4 acc = {0.f, 0.f, 0.f, 0.f};
#pragma unroll
            for (int ks = 0; ks < DH / 32; ++ks) {
                bf16x8 a = *(const bf16x8*)(QKV +
                    (size_t)(rowQ + mj * 16 + lr) * 768 + 256 + h * DH + ks * 32 + l16 * 8);
                bf16x8 b = *(const bf16x8*)(QKV +
                    (size_t)(rowQ + ni * 16 + lr) * 768 + h * DH + ks * 32 + l16 * 8);
                acc = __builtin_amdgcn_mfma_f32_16x16x32_bf16(a, b, acc, 0, 0, 0);
            }
#pragma unroll
            for (int r = 0; r < 4; ++r)
                S_lds[mj * 16 + l16 * 4 + r][ni * 16 + lr] = acc[r];
        }
        __syncthreads();
        if (tid < 48) {
            int i = tid;
            if (i < 34) {
                int ti = tok_lds[i];
                float sc[34];
                float mx = -1e30f;
#pragma unroll
                for (int j = 0; j < 34; ++j) {
                    float v = (ti && tok_lds[j]) ? S_lds[j][i] * scale : -1e9f;
                    sc[j] = v;
                    mx = fmaxf(mx, v);
                }
                float sum = 0.f;
#pragma unroll
                for (int j = 0; j < 34; ++j) {
                    sc[j] = __expf(sc[j] - mx);
                    sum += sc[j];
                }
                float inv = 1.f / sum;
#pragma unroll
                for (int j = 0; j < 34; ++j) P_lds[i][j] = f2us(sc[j] * inv);
#pragma unroll
                for (int j = 34; j < 64; ++j) P_lds[i][j] = 0;
            } else {
#pragma unroll
                for (int j = 0; j < 64; ++j) P_lds[i][j] = 0;
            }
        }
        __syncthreads();
        for (int nt = wv; nt < DH / 16; nt += 4) {
            f32x4 acc[3];
#pragma unroll
            for (int mi = 0; mi < 3; ++mi) acc[mi] = (f32x4){0.f, 0.f, 0.f, 0.f};
#pragma unroll
            for (int ks = 0; ks < 2; ++ks) {
                int j0 = ks * 32 + l16 * 8;
                int d = h * DH + nt * 16 + lr;
                // unaligned-safe LDS read (2B aligned); garbage beyond j=34
                // multiplies P zeros
                bf16x8 bv;
                __builtin_memcpy(&bv, VT_lds + d * 42 + j0, 16);
#pragma unroll
                for (int mi = 0; mi < 3; ++mi) {
                    bf16x8 av = *(const bf16x8*)(&P_lds[0][0] + (mi * 16 + lr) * 72 + j0);
                    acc[mi] = __builtin_amdgcn_mfma_f32_16x16x32_bf16(av, bv, acc[mi], 0, 0, 0);
                }
            }
#pragma unroll
            for (int mi = 0; mi < 3; ++mi)
#pragma unroll
                for (int r = 0; r < 4; ++r) {
                    int i = mi * 16 + l16 * 4 + r;
                    if (i < 34)
                        O[(size_t)(rowQ + i) * 256 + h * DH + nt * 16 + lr] =
                            f2bf(acc[mi][r]);
                }
        }
        __syncthreads();
    }
}

// ---------------- wave-per-row LayerNorm ----------------
template <bool RELU>
__global__ __launch_bounds__(256) void ln_rows(__hip_bfloat16* __restrict__ Z,
                                               const float* __restrict__ g,
                                               const float* __restrict__ b) {
    int row = (blockIdx.x << 2) + (threadIdx.x >> 6);
    int l = threadIdx.x & 63;
    ushort4 u = ((ushort4*)(Z + (size_t)row * DD))[l];
    float x0 = us2f(u.x), x1 = us2f(u.y), x2 = us2f(u.z), x3 = us2f(u.w);
    float s = x0 + x1 + x2 + x3;
    for (int o = 1; o < 64; o <<= 1) s += __shfl_xor(s, o, 64);
    float mean = s * (1.f / 256.f);
    float d0 = x0 - mean, d1 = x1 - mean, d2 = x2 - mean, d3 = x3 - mean;
    float q = d0 * d0 + d1 * d1 + d2 * d2 + d3 * d3;
    for (int o = 1; o < 64; o <<= 1) q += __shfl_xor(q, o, 64);
    float rst = rsqrtf(q * (1.f / 256.f) + 1e-5f);
    float4 gg = ((const float4*)g)[l], bb = ((const float4*)b)[l];
    float y0 = d0 * rst * gg.x + bb.x, y1 = d1 * rst * gg.y + bb.y;
    float y2 = d2 * rst * gg.z + bb.z, y3 = d3 * rst * gg.w + bb.w;
    if (RELU) {
        y0 = fmaxf(y0, 0.f); y1 = fmaxf(y1, 0.f);
        y2 = fmaxf(y2, 0.f); y3 = fmaxf(y3, 0.f);
    }
    union { __hip_bfloat16 h[4]; ushort4 v; } pk;
    pk.h[0] = f2bf(y0); pk.h[1] = f2bf(y1); pk.h[2] = f2bf(y2); pk.h[3] = f2bf(y3);
    ((ushort4*)(Z + (size_t)row * DD))[l] = pk.v;
}

// ---------------- final head ----------------
__global__ __launch_bounds__(256) void head2(const __hip_bfloat16* __restrict__ Y1,
                                             const float* __restrict__ w,
                                             const float* __restrict__ b,
                                             float* __restrict__ out) {
    __shared__ float red[8];
    int i = blockIdx.x, tid = threadIdx.x;
    float s = bf2f(Y1[(size_t)i * 512 + tid]) * w[tid] +
              bf2f(Y1[(size_t)i * 512 + 256 + tid]) * w[256 + tid];
    float bs = block_reduce_sum256(s, red);
    if (tid == 0) out[i] = bs + b[0];
}

__global__ void lstab_k(const float* __restrict__ SC, float* __restrict__ dst) {
    if (threadIdx.x == 0 && blockIdx.x == 0) {
        float s = 0.f;
        for (int m = 0; m < 3; ++m)
            s += fabsf(sqrtf(SC[6 + m]) - sqrtf(SC[9 + m]));
        dst[0] = s;
    }
}

__global__ void gcn_bias_cat(const float* __restrict__ gcn_b, float* __restrict__ Bcat) {
    int m = blockIdx.x, l = blockIdx.y, c = threadIdx.x;
    Bcat[l * 768 + m * 256 + c] = gcn_b[(m * 2 + l) * 256 + c];
}

// ===========================================================================
#define GEMM(OUTM_, BIAS_, RELU_, A_, Bt_, BI_, C_, M_, N_, K_)                 \
    gemm_mfma<OUTM_, BIAS_, RELU_>                                              \
        <<<dim3((N_) / 128, (M_) / 128), 256, 0, stream>>>(                     \
            (const ushort*)(A_), (const ushort*)(Bt_), (BI_), (void*)(C_),      \
            (M_), (N_), (K_))
#define GEMMZ(A_, Bt_, C_, M_, N_, K_, Z_)                                      \
    gemm_mfma<5, false, false>                                                  \
        <<<dim3((N_) / 128, (M_) / 128, (Z_)), 256, 0, stream>>>(               \
            (const ushort*)(A_), (const ushort*)(Bt_), (const float*)nullptr,   \
            (void*)(C_), (M_), (N_), (K_))
#define GEMMT(OUTM_, BIAS_, RELU_, A_, Bt_, BI_, C_, M_, N_, K_)                \
    gemm_thin<OUTM_, BIAS_, RELU_>                                              \
        <<<dim3((N_) / 128, (M_) / 64), 256, 0, stream>>>(                      \
            (const ushort*)(A_), (const ushort*)(Bt_), (BI_), (void*)(C_),      \
            (M_), (N_), (K_))

extern "C" void kernel_launch(void* const* d_in, const int* in_sizes, int n_in,
                              void* d_out, int out_size, void* d_ws, size_t ws_size,
                              hipStream_t stream) {
    (void)in_sizes; (void)n_in; (void)out_size; (void)ws_size;
    const float* emb0 = (const float*)d_in[0];
    const float* emb1 = (const float*)d_in[1];
    const float* emb2 = (const float*)d_in[2];
    const void* msk0 = d_in[3];
    const void* msk1 = d_in[4];
    const void* msk2 = d_in[5];
    const float* simi_w = (const float*)d_in[6];
    const float* simi_b = (const float*)d_in[7];
    const float* bn_g = (const float*)d_in[8];
    const float* bn_b = (const float*)d_in[9];
    const float* simi_eps = (const float*)d_in[10];
    const float* dissim = (const float*)d_in[11];
    const float* gcn_w = (const float*)d_in[12];
    const float* gcn_b = (const float*)d_in[13];
    const float* adapt_w = (const float*)d_in[14];
    const float* adapt_b = (const float*)d_in[15];
    const float* type_emb = (const float*)d_in[16];
    const float* attn_w = (const float*)d_in[17];
    const float* attn_b = (const float*)d_in[18];
    const float* ffn_w1 = (const float*)d_in[19];
    const float* ffn_b1 = (const float*)d_in[20];
    const float* ffn_w2 = (const float*)d_in[21];
    const float* ffn_b2 = (const float*)d_in[22];
    const float* ln_g = (const float*)d_in[23];
    const float* ln_b = (const float*)d_in[24];
    const float* out_w1 = (const float*)d_in[25];
    const float* out_b1 = (const float*)d_in[26];
    const float* out_w2 = (const float*)d_in[27];
    const float* out_b2 = (const float*)d_in[28];
    float* out = (float*)d_out;

    const int ACH = 1024, ACROWS = ACH * LTOK;  // 34816 rows/chunk, 2 chunks

    // ---- workspace layout (~185 MB) ----
    char* wp = (char*)d_ws;
    auto alloc = [&](size_t bytes) -> char* {
        char* p = wp;
        wp += (bytes + 255) & ~(size_t)255;
        return p;
    };
    __hip_bfloat16* Zb = (__hip_bfloat16*)alloc((size_t)NN * LTOK * DD * 2);  // 35.7MB
    char* UN = alloc((size_t)80 * 1024 * 1024);  // union: S3b / QKVb|Ob / Hfb / SLICE
    ushort* S3b = (ushort*)UN;                                          // 25.2MB
    __hip_bfloat16* QKVb = (__hip_bfloat16*)UN;                         // 53.5MB
    __hip_bfloat16* Ob = (__hip_bfloat16*)(UN + (size_t)ACROWS * 768 * 2);  // 17.8MB
    __hip_bfloat16* Hfb = (__hip_bfloat16*)UN;
    __hip_bfloat16* SLICEB = (__hip_bfloat16*)UN;   // bf16 split-K slices
    __hip_bfloat16* Sb = (__hip_bfloat16*)alloc((size_t)NN * NN * 2);
    float* P3 = (float*)alloc((size_t)3 * NN * DD * 4);
    float* E0 = (float*)alloc((size_t)NN * DD * 4);
    __hip_bfloat16* Eb3 = (__hip_bfloat16*)alloc((size_t)3 * NN * DD * 2);
    __hip_bfloat16* T1b3 = (__hip_bfloat16*)alloc((size_t)3 * NN * DD * 2);
    __hip_bfloat16* T2b3 = (__hip_bfloat16*)alloc((size_t)3 * NN * DD * 2);
    ushort* XB6 = (ushort*)alloc((size_t)6 * NN * DD * 2);
    __hip_bfloat16* TBt3 = (__hip_bfloat16*)alloc((size_t)3 * NN * DD * 2);
    __hip_bfloat16* HB3 = (__hip_bfloat16*)alloc((size_t)NN * 768 * 2);
    __hip_bfloat16* HB2_3 = (__hip_bfloat16*)alloc((size_t)NN * 768 * 2);
    float* I0 = (float*)alloc((size_t)NN * DD * 4);
    float* I1 = (float*)alloc((size_t)NN * DD * 4);
    float* I2 = (float*)alloc((size_t)NN * DD * 4);
    __hip_bfloat16* Y1b = (__hip_bfloat16*)alloc((size_t)NN * 512 * 2);
    __hip_bfloat16* simi_wt = (__hip_bfloat16*)alloc((size_t)9 * 65536 * 2);
    __hip_bfloat16* gcn_wt = (__hip_bfloat16*)alloc((size_t)6 * 65536 * 2);
    __hip_bfloat16* attn_wt = (__hip_bfloat16*)alloc((size_t)8 * 65536 * 2);
    __hip_bfloat16* w1t = (__hip_bfloat16*)alloc((size_t)2 * 262144 * 2);
    __hip_bfloat16* w2t = (__hip_bfloat16*)alloc((size_t)2 * 262144 * 2);
    __hip_bfloat16* ow1t = (__hip_bfloat16*)alloc((size_t)8704 * 512 * 2);
    float* PET = (float*)alloc(32 * 256 * 4);
    float* MV6 = (float*)alloc(6 * 512 * 4);
    float* SQ6 = (float*)alloc(6 * NN * 4);
    float* PART = (float*)alloc(4096 * 4);
    float* SC = (float*)alloc(64 * 4);   // 6..8 |P|^2, 9..11 |E|^2, 16 mode, 20..25 bw
    float* Bcat = (float*)alloc(1536 * 4);
    int* TOK = (int*)alloc((size_t)NN * LTOK * 4);
    int* MK = (int*)alloc((size_t)3 * NN * 4);

    // ---- weight transpose-convert (z-batched: 6 launches) ----
    cvt_transz<<<dim3(8, 8, 9), 256, 0, stream>>>(simi_w, simi_wt, 256, 256);
    cvt_transz<<<dim3(8, 8, 6), 256, 0, stream>>>(gcn_w, gcn_wt, 256, 256);
    cvt_transz<<<dim3(8, 8, 8), 256, 0, stream>>>(attn_w, attn_wt, 256, 256);
    cvt_transz<<<dim3(32, 8, 2), 256, 0, stream>>>(ffn_w1, w1t, 256, 1024);
    cvt_transz<<<dim3(8, 32, 2), 256, 0, stream>>>(ffn_w2, w2t, 1024, 256);
    cvt_transz<<<dim3(16, 272, 1), 256, 0, stream>>>(out_w1, ow1t, 8704, 512);

    // ---- prep ----
    pe_table<<<32, 256, 0, stream>>>(type_emb, PET);
    gather_e0<<<NN, 256, 0, stream>>>(emb0, E0, Eb3);
    cvt_flat<<<512, 256, 0, stream>>>(emb1, Eb3 + (size_t)NN * DD, NN * DD / 4);
    cvt_flat<<<512, 256, 0, stream>>>(emb2, Eb3 + (size_t)2 * NN * DD, NN * DD / 4);
    detect_mode<<<1, 64, 0, stream>>>(msk1, (int*)SC + 16);
    build_masks<<<(NN * LTOK + 255) / 256, 256, 0, stream>>>(msk0, msk1, msk2,
                                                             (int*)SC + 16, MK, TOK);
    gcn_bias_cat<<<dim3(3, 2), 256, 0, stream>>>(gcn_b, Bcat);

    const float* Ef[3] = {E0, emb1, emb2};

    // ---- Stage A ----
    for (int m = 0; m < 3; ++m)
        sumsq_partial<<<512, 256, 0, stream>>>(Ef[m], NN * DD, PART + 512 + m * 512);
    gemm_batch<1, true, true, false><<<dim3(2, 16, 3), 256, 0, stream>>>(
        (const ushort*)Eb3, 256, (size_t)NN * DD, (const ushort*)simi_wt,
        (size_t)3 * 65536, simi_b, 3 * 256, T1b3, 256, (size_t)NN * DD,
        nullptr, NN, 256, 256);
    gemm_batch<1, true, true, false><<<dim3(2, 16, 3), 256, 0, stream>>>(
        (const ushort*)T1b3, 256, (size_t)NN * DD, (const ushort*)(simi_wt + 65536),
        (size_t)3 * 65536, simi_b + 256, 3 * 256, T2b3, 256, (size_t)NN * DD,
        nullptr, NN, 256, 256);
    gemm_batch<0, false, true, true><<<dim3(2, 16, 3), 256, 0, stream>>>(
        (const ushort*)T2b3, 256, (size_t)NN * DD, (const ushort*)(simi_wt + 2 * 65536),
        (size_t)3 * 65536, simi_b + 2 * 256, 3 * 256, P3, 256, (size_t)NN * DD,
        PART + 2048, NN, 256, 256);
    reduce6<<<6, 256, 0, stream>>>(PART, SC);

    colstats6<<<dim3(256, 6), 256, 0, stream>>>(P3, E0, emb1, emb2, MV6, NN);
    bn_fuse6<<<dim3(NN, 6), 256, 0, stream>>>(P3, E0, emb1, emb2, MV6, bn_g, bn_b,
                                              XB6, SQ6);
    bw_fast6<<<6, 256, 0, stream>>>(SQ6, bn_b, SC + 20);

    // z=3 parallel masked GK planes into S3b (bf16, thin tile, UN region)
    gemm_dist_gk3<<<dim3(16, 32, 3), 256, 0, stream>>>(XB6, SQ6, SC + 20, MK,
                                                       simi_eps, S3b);

    // ---- Stage B (bf16 split-K slices) ----
    agg_cvt3<<<4096, 256, 0, stream>>>((const ushort4*)S3b, MK, MK + NN, MK + 2 * NN,
                                       dissim, (ushort4*)Sb);
    gemm_batch<2, false, false, false><<<dim3(2, 16, 3), 256, 0, stream>>>(
        (const ushort*)Eb3, 256, (size_t)NN * DD, (const ushort*)gcn_wt,
        (size_t)2 * 65536, nullptr, 0, TBt3, 256, (size_t)NN * DD,
        nullptr, NN, 256, 256);
    GEMMZ(Sb, TBt3, SLICEB, NN, 768, NN, 8);
    slice_fin_b<8, true><<<1536, 256, 0, stream>>>((const ushort4*)SLICEB, Bcat, HB3,
                                                   768, (size_t)NN * 768);
    gemm_batch<2, false, false, false><<<dim3(2, 16, 3), 256, 0, stream>>>(
        (const ushort*)HB3, 768, (size_t)256, (const ushort*)(gcn_wt + 65536),
        (size_t)2 * 65536, nullptr, 0, TBt3, 256, (size_t)NN * DD,
        nullptr, NN, 256, 256);
    GEMMZ(Sb, TBt3, SLICEB, NN, 768, NN, 8);
    slice_fin_b<8, true><<<1536, 256, 0, stream>>>((const ushort4*)SLICEB, Bcat + 768,
                                                   HB2_3, 768, (size_t)NN * 768);
    float* IMP[3] = {I0, I1, I2};
    for (int m = 0; m < 3; ++m)
        impute_k<<<NN, 256, 0, stream>>>(Ef[m], HB2_3 + m * 256, 768,
                                         adapt_w + m * 256, adapt_b + m,
                                         MK + m * NN, IMP[m]);

    // ---- Stage C: 34-token transformer (2 chunks of 1024 samples) ----
    build_z2<<<NN * LTOK * 64 / 256, 256, 0, stream>>>(
        (const float4*)emb0, (const float4*)I0, (const float4*)I1, (const float4*)I2,
        (const float4*)PET, (const float4*)type_emb, (ushort4*)Zb);
    const int NCHUNK = NN / ACH;  // 2
    for (int li = 0; li < 2; ++li) {
        for (int c = 0; c < NCHUNK; ++c) {
            __hip_bfloat16* Zc = Zb + (size_t)c * ACROWS * DD;
            // fused QKV projection, thin tile, pure row-major [rows][768]
            GEMMT(1, true, false, Zc, attn_wt + (size_t)(li * 4) * 65536,
                  attn_b + li * 4 * 256, QKVb, ACROWS, 768, 256);
            if (li == 0)
                attn_mfma<64, 4><<<ACH, 256, 0, stream>>>(
                    (const ushort*)QKVb, TOK, Ob, c * ACH);
            else
                attn_mfma<256, 1><<<ACH, 256, 0, stream>>>(
                    (const ushort*)QKVb, TOK, Ob, c * ACH);
            GEMMT(3, true, false, Ob, attn_wt + (size_t)(li * 4 + 3) * 65536,
                  attn_b + (li * 4 + 3) * 256, Zc, ACROWS, 256, 256);
        }
        ln_rows<false><<<NN * LTOK / 4, 256, 0, stream>>>(Zb, ln_g + (li * 2 + 0) * 256,
                                                          ln_b + (li * 2 + 0) * 256);
        for (int c = 0; c < NCHUNK; ++c) {
            __hip_bfloat16* Zc = Zb + (size_t)c * ACROWS * DD;
            GEMM(1, true, true, Zc, w1t + (size_t)li * 262144, ffn_b1 + li * 1024,
                 Hfb, ACROWS, 1024, 256);
            GEMMT(3, true, false, Hfb, w2t + (size_t)li * 262144, ffn_b2 + li * 256,
                  Zc, ACROWS, 256, 1024);
        }
        ln_rows<true><<<NN * LTOK / 4, 256, 0, stream>>>(Zb, ln_g + (li * 2 + 1) * 256,
                                                         ln_b + (li * 2 + 1) * 256);
    }

    // ---- head (bf16 split-K Z=8, SLICEB in UN which is now free) ----
    GEMMZ(Zb, ow1t, SLICEB, NN, 512, LTOK * DD, 8);
    slice_fin_b<8, true><<<1024, 256, 0, stream>>>((const ushort4*)SLICEB, out_b1, Y1b,
                                                   512, (size_t)NN * 512);
    head2<<<NN, 256, 0, stream>>>(Y1b, out_w2, out_b2, out);
    lstab_k<<<1, 64, 0, stream>>>(SC, out + NN);
}

// Round 18
// 850.538 us; speedup vs baseline: 1.5628x; 1.0177x over previous
//
#include <hip/hip_runtime.h>
#include <hip/hip_bf16.h>

// ---------------------------------------------------------------------------
// M3Care forward — bf16 MFMA GEMMs (global_load_lds staging + XCD swizzle +
// bf16 split-K + thin-tile z-batched small GEMMs + thin-tile GEMMs incl.
// row-major fused QKV), fused dist+gk+sim (z=3 parallel bf16 planes, thin
// tile, 1-exp gk3), z-batched weight transposes, PE table, MFMA attention
// with in-LDS V-transpose, closed-form bandwidth, batched BN.
// N=2048, D=256, NE=34, heads=(4,1).
// ---------------------------------------------------------------------------

#define NN 2048
#define DD 256
#define LTOK 34

typedef __attribute__((ext_vector_type(8))) short bf16x8;
typedef __attribute__((ext_vector_type(4))) float f32x4;

__device__ __forceinline__ float bf2f(__hip_bfloat16 x) { return __bfloat162float(x); }
__device__ __forceinline__ __hip_bfloat16 f2bf(float x) { return __float2bfloat16(x); }
__device__ __forceinline__ float us2f(ushort u) {
    unsigned x = (unsigned)u << 16;
    float f;
    __builtin_memcpy(&f, &x, 4);
    return f;
}
__device__ __forceinline__ ushort f2us(float x) {
    __hip_bfloat16 h = f2bf(x);
    ushort u;
    __builtin_memcpy(&u, &h, 2);
    return u;
}

// ---------------- block reduce (blockDim.x == 256) ----------------
__device__ __forceinline__ float block_reduce_sum256(float v, float* red) {
    for (int o = 32; o > 0; o >>= 1) v += __shfl_down(v, o, 64);
    int tid = threadIdx.x;
    if ((tid & 63) == 0) red[tid >> 6] = v;
    __syncthreads();
    float s = red[0] + red[1] + red[2] + red[3];
    __syncthreads();
    return s;
}

// XCD-chunked bijective remap (T1, m204 variant).
__device__ __forceinline__ int xcd_remap(int lin, int nwg) {
    int q = nwg >> 3, r = nwg & 7;
    int xcd = lin & 7, pos = lin >> 3;
    return (xcd < r ? xcd * (q + 1) : r * (q + 1) + (xcd - r) * q) + pos;
}

// Stage one 128x64 bf16 tile via global_load_lds (16B/lane), linear LDS dest,
// inverse-XOR-swizzled per-lane GLOBAL source (rule #21).
__device__ __forceinline__ void stage_tile(const ushort* __restrict__ src,
                                           ushort* lds, int grow0, size_t ldk,
                                           int k0, int wv, int l) {
#pragma unroll
    for (int c = 0; c < 4; ++c) {
        int rowbase = wv * 32 + c * 8;
        int row = rowbase + (l >> 3);
        int sx = ((l & 7) ^ (row & 7)) * 8;
        __builtin_amdgcn_global_load_lds(
            (const __attribute__((address_space(1))) void*)(src + (size_t)(grow0 + row) * ldk + k0 + sx),
            (__attribute__((address_space(3))) void*)(lds + rowbase * 64), 16, 0, 0);
    }
}

// 64-row variant (A-tile of the thin GEMM)
__device__ __forceinline__ void stage_tile64(const ushort* __restrict__ src,
                                             ushort* lds, int grow0, size_t ldk,
                                             int k0, int wv, int l) {
#pragma unroll
    for (int c = 0; c < 2; ++c) {
        int rowbase = wv * 16 + c * 8;
        int row = rowbase + (l >> 3);
        int sx = ((l & 7) ^ (row & 7)) * 8;
        __builtin_amdgcn_global_load_lds(
            (const __attribute__((address_space(1))) void*)(src + (size_t)(grow0 + row) * ldk + k0 + sx),
            (__attribute__((address_space(3))) void*)(lds + rowbase * 64), 16, 0, 0);
    }
}

// MFMA inner step over the staged 128x64 tiles (one kk half)
#define MFMA_STEP(ACC)                                                          \
    {                                                                           \
        bf16x8 av[4], bv[4];                                                    \
        _Pragma("unroll") for (int f = 0; f < 4; ++f) {                         \
            int ra = wr * 64 + f * 16 + lr;                                     \
            av[f] = *(const bf16x8*)(As + ra * 64 + (((kk * 4 + l16) ^ (ra & 7)) * 8)); \
            int rb = wc * 64 + f * 16 + lr;                                     \
            bv[f] = *(const bf16x8*)(Bs + rb * 64 + (((kk * 4 + l16) ^ (rb & 7)) * 8)); \
        }                                                                       \
        _Pragma("unroll") for (int mf = 0; mf < 4; ++mf)                        \
            _Pragma("unroll") for (int nf = 0; nf < 4; ++nf)                    \
                ACC[mf][nf] = __builtin_amdgcn_mfma_f32_16x16x32_bf16(          \
                    av[mf], bv[nf], ACC[mf][nf], 0, 0, 0);                      \
    }

// Thin-tile (64-row A) MFMA inner step
#define MFMA_STEP_T(ACC)                                                        \
    {                                                                           \
        bf16x8 av[2], bv[4];                                                    \
        _Pragma("unroll") for (int f = 0; f < 2; ++f) {                         \
            int ra = wr * 32 + f * 16 + lr;                                     \
            av[f] = *(const bf16x8*)(As + ra * 64 + (((kk * 4 + l16) ^ (ra & 7)) * 8)); \
        }                                                                       \
        _Pragma("unroll") for (int f = 0; f < 4; ++f) {                         \
            int rb = wc * 64 + f * 16 + lr;                                     \
            bv[f] = *(const bf16x8*)(Bs + rb * 64 + (((kk * 4 + l16) ^ (rb & 7)) * 8)); \
        }                                                                       \
        _Pragma("unroll") for (int mf = 0; mf < 2; ++mf)                        \
            _Pragma("unroll") for (int nf = 0; nf < 4; ++nf)                    \
                ACC[mf][nf] = __builtin_amdgcn_mfma_f32_16x16x32_bf16(          \
                    av[mf], bv[nf], ACC[mf][nf], 0, 0, 0);                      \
    }

// ---------------------------------------------------------------------------
// bf16 MFMA GEMM (big/split-K): C[M,N] = A[M,K] @ Bt[N,K]^T (+bias)
// OUTM: 0 = f32 out (slice z*M*N), 1 = bf16 out, 3 = bf16 in-place add,
//       5 = bf16 split-K slice out.
// ---------------------------------------------------------------------------
template <int OUTM, bool BIAS, bool RELU>
__global__ __launch_bounds__(256) void gemm_mfma(
    const ushort* __restrict__ A, const ushort* __restrict__ Bt,
    const float* __restrict__ bias, void* __restrict__ Cout,
    int M, int N, int K)
{
    __shared__ __align__(16) ushort As[128 * 64];
    __shared__ __align__(16) ushort Bs[128 * 64];
    const int gx = gridDim.x;
    int lin = xcd_remap(blockIdx.y * gx + blockIdx.x, gx * gridDim.y);
    const int bm = (lin / gx) * 128, bn = (lin % gx) * 128;
    const int tid = threadIdx.x;
    const int l = tid & 63, wv = tid >> 6;
    const int wr = wv >> 1, wc = wv & 1;
    const int l16 = l >> 4, lr = l & 15;
    const int kpz = K / gridDim.z;
    const int kbeg = blockIdx.z * kpz, kend = kbeg + kpz;
    f32x4 zero = {0.f, 0.f, 0.f, 0.f};
    f32x4 acc[4][4];
#pragma unroll
    for (int i = 0; i < 4; ++i)
#pragma unroll
        for (int j = 0; j < 4; ++j) acc[i][j] = zero;

    for (int k0 = kbeg; k0 < kend; k0 += 64) {
        stage_tile(A, As, bm, K, k0, wv, l);
        stage_tile(Bt, Bs, bn, K, k0, wv, l);
        __syncthreads();
#pragma unroll
        for (int kk = 0; kk < 2; ++kk) MFMA_STEP(acc)
        __syncthreads();
    }
    float* Cf = (float*)Cout + (size_t)blockIdx.z * M * N;
    __hip_bfloat16* Cb = (__hip_bfloat16*)Cout + (size_t)blockIdx.z * M * N;
#pragma unroll
    for (int mf = 0; mf < 4; ++mf) {
#pragma unroll
        for (int nf = 0; nf < 4; ++nf) {
            int col = bn + wc * 64 + nf * 16 + lr;
            float bb = BIAS ? bias[col] : 0.f;
#pragma unroll
            for (int r = 0; r < 4; ++r) {
                int row = bm + wr * 64 + mf * 16 + l16 * 4 + r;
                float v = acc[mf][nf][r] + bb;
                if (OUTM == 3)
                    v += bf2f(((const __hip_bfloat16*)Cout)[(size_t)row * N + col]);
                if (RELU) v = fmaxf(v, 0.f);
                if (OUTM == 0)
                    Cf[(size_t)row * N + col] = v;
                else if (OUTM == 5)
                    Cb[(size_t)row * N + col] = f2bf(v);
                else
                    ((__hip_bfloat16*)Cout)[(size_t)row * N + col] = f2bf(v);
            }
        }
    }
}

// ---------------------------------------------------------------------------
// Thin-tile GEMM: 64x128 tile, 24KB LDS. OUTM: 1 = bf16 out, 3 = add.
// ---------------------------------------------------------------------------
template <int OUTM, bool BIAS, bool RELU>
__global__ __launch_bounds__(256) void gemm_thin(
    const ushort* __restrict__ A, const ushort* __restrict__ Bt,
    const float* __restrict__ bias, void* __restrict__ Cout,
    int M, int N, int K)
{
    __shared__ __align__(16) ushort As[64 * 64];
    __shared__ __align__(16) ushort Bs[128 * 64];
    const int gx = gridDim.x;
    int lin = xcd_remap(blockIdx.y * gx + blockIdx.x, gx * gridDim.y);
    const int bm = (lin / gx) * 64, bn = (lin % gx) * 128;
    const int tid = threadIdx.x;
    const int l = tid & 63, wv = tid >> 6;
    const int wr = wv >> 1, wc = wv & 1;
    const int l16 = l >> 4, lr = l & 15;
    f32x4 zero = {0.f, 0.f, 0.f, 0.f};
    f32x4 acc[2][4];
#pragma unroll
    for (int i = 0; i < 2; ++i)
#pragma unroll
        for (int j = 0; j < 4; ++j) acc[i][j] = zero;

    for (int k0 = 0; k0 < K; k0 += 64) {
        stage_tile64(A, As, bm, K, k0, wv, l);
        stage_tile(Bt, Bs, bn, K, k0, wv, l);
        __syncthreads();
#pragma unroll
        for (int kk = 0; kk < 2; ++kk) MFMA_STEP_T(acc)
        __syncthreads();
    }
#pragma unroll
    for (int mf = 0; mf < 2; ++mf) {
#pragma unroll
        for (int nf = 0; nf < 4; ++nf) {
            int col = bn + wc * 64 + nf * 16 + lr;
            float bb = BIAS ? bias[col] : 0.f;
#pragma unroll
            for (int r = 0; r < 4; ++r) {
                int row = bm + wr * 32 + mf * 16 + l16 * 4 + r;
                float v = acc[mf][nf][r] + bb;
                if (OUTM == 3)
                    v += bf2f(((const __hip_bfloat16*)Cout)[(size_t)row * N + col]);
                if (RELU) v = fmaxf(v, 0.f);
                ((__hip_bfloat16*)Cout)[(size_t)row * N + col] = f2bf(v);
            }
        }
    }
}

// ---------------------------------------------------------------------------
// z-batched THIN small GEMM (K<=256, 64-row A tile): grid (N/128, M/64, Z).
// OUTM: 0=f32 out, 1=bf16 out, 2=bf16 transposed [col*M+row]. PSUM: sum v^2.
// ---------------------------------------------------------------------------
template <int OUTM, bool RELU, bool BIAS, bool PSUM>
__global__ __launch_bounds__(256) void gemm_batch_t(
    const ushort* __restrict__ A, int lda, size_t aoffZ,
    const ushort* __restrict__ Bt, size_t boffZ,
    const float* __restrict__ bias, int biasoffZ,
    void* __restrict__ Cout, int ldc, size_t coffZ,
    float* __restrict__ psum, int M, int N, int K)
{
    __shared__ __align__(16) ushort As[64 * 64];
    __shared__ __align__(16) ushort Bs[128 * 64];
    __shared__ float red[8];
    const int gx = gridDim.x;
    const int lin0 = blockIdx.y * gx + blockIdx.x;
    int lin = xcd_remap(lin0, gx * gridDim.y);
    const int bm = (lin / gx) * 64, bn = (lin % gx) * 128;
    const int z = blockIdx.z;
    A += (size_t)z * aoffZ;
    Bt += (size_t)z * boffZ;
    if (BIAS) bias += (size_t)z * biasoffZ;
    const int tid = threadIdx.x;
    const int l = tid & 63, wv = tid >> 6;
    const int wr = wv >> 1, wc = wv & 1;
    const int l16 = l >> 4, lr = l & 15;
    f32x4 zero = {0.f, 0.f, 0.f, 0.f};
    f32x4 acc[2][4];
#pragma unroll
    for (int i = 0; i < 2; ++i)
#pragma unroll
        for (int j = 0; j < 4; ++j) acc[i][j] = zero;

    for (int k0 = 0; k0 < K; k0 += 64) {
        stage_tile64(A, As, bm, lda, k0, wv, l);
        stage_tile(Bt, Bs, bn, K, k0, wv, l);
        __syncthreads();
#pragma unroll
        for (int kk = 0; kk < 2; ++kk) MFMA_STEP_T(acc)
        __syncthreads();
    }
    float lsq = 0.f;
#pragma unroll
    for (int mf = 0; mf < 2; ++mf) {
#pragma unroll
        for (int nf = 0; nf < 4; ++nf) {
            int col = bn + wc * 64 + nf * 16 + lr;
            float bb = BIAS ? bias[col] : 0.f;
#pragma unroll
            for (int r = 0; r < 4; ++r) {
                int row = bm + wr * 32 + mf * 16 + l16 * 4 + r;
                float v = acc[mf][nf][r] + bb;
                if (RELU) v = fmaxf(v, 0.f);
                if (PSUM) lsq += v * v;
                if (OUTM == 0)
                    ((float*)Cout + (size_t)z * coffZ)[(size_t)row * ldc + col] = v;
                else if (OUTM == 2)
                    ((__hip_bfloat16*)Cout + (size_t)z * coffZ)[(size_t)col * M + row] = f2bf(v);
                else
                    ((__hip_bfloat16*)Cout + (size_t)z * coffZ)[(size_t)row * ldc + col] = f2bf(v);
            }
        }
    }
    if (PSUM) {
        float bs = block_reduce_sum256(lsq, red);
        if (tid == 0) psum[z * gx * gridDim.y + lin0] = bs;
    }
}

// ---------------------------------------------------------------------------
// Fused dual-distance + multi-bandwidth GK, z = modal (parallel bf16 planes),
// THIN 64x128 tile. gk3(d) = t + t^2 + t^4, ONE exp per plane. Grid(16,32,3).
// ---------------------------------------------------------------------------
__global__ __launch_bounds__(256) void gemm_dist_gk3(
    const ushort* __restrict__ XB6, const float* __restrict__ SQ6,
    const float* __restrict__ bws, const int* __restrict__ MK,
    const float* __restrict__ epsp, ushort* __restrict__ S3b)
{
    __shared__ __align__(16) ushort As[64 * 64];
    __shared__ __align__(16) ushort Bs[128 * 64];
    const int gx = gridDim.x;
    int lin = xcd_remap(blockIdx.y * gx + blockIdx.x, gx * gridDim.y);
    const int bm = (lin / gx) * 64, bn = (lin % gx) * 128;
    const int z = blockIdx.z;
    const ushort* XB = XB6 + (size_t)(2 * z) * NN * DD;
    const float* SQ = SQ6 + (size_t)(2 * z) * NN;
    const int* mk = MK + (size_t)z * NN;
    ushort* S = S3b + (size_t)z * NN * NN;
    const int tid = threadIdx.x;
    const int l = tid & 63, wv = tid >> 6;
    const int wr = wv >> 1, wc = wv & 1;
    const int l16 = l >> 4, lr = l & 15;
    f32x4 zero = {0.f, 0.f, 0.f, 0.f};
    f32x4 acc1[2][4], acc2[2][4];
#pragma unroll
    for (int i = 0; i < 2; ++i)
#pragma unroll
        for (int j = 0; j < 4; ++j) { acc1[i][j] = zero; acc2[i][j] = zero; }

    for (int k0 = 0; k0 < 256; k0 += 64) {
        stage_tile64(XB, As, bm, 256, k0, wv, l);
        stage_tile(XB, Bs, bn, 256, k0, wv, l);
        __syncthreads();
#pragma unroll
        for (int kk = 0; kk < 2; ++kk) MFMA_STEP_T(acc1)
        __syncthreads();
    }
    const ushort* X1 = XB + (size_t)NN * DD;
    for (int k0 = 0; k0 < 256; k0 += 64) {
        stage_tile64(X1, As, bm, 256, k0, wv, l);
        stage_tile(X1, Bs, bn, 256, k0, wv, l);
        __syncthreads();
#pragma unroll
        for (int kk = 0; kk < 2; ++kk) MFMA_STEP_T(acc2)
        __syncthreads();
    }
    float eps = 1.f / (1.f + __expf(-epsp[z]));
    const float cnn = 1.f / ((float)NN * NN - (float)NN);
    float ia4 = 0.5f / (bws[2 * z] * cnn);
    float ib4 = 0.5f / (bws[2 * z + 1] * cnn);
#pragma unroll
    for (int mf = 0; mf < 2; ++mf) {
#pragma unroll
        for (int nf = 0; nf < 4; ++nf) {
            int col = bn + wc * 64 + nf * 16 + lr;
            int mcol = mk[col];
            float sqc0 = SQ[col], sqc1 = SQ[NN + col];
#pragma unroll
            for (int r = 0; r < 4; ++r) {
                int row = bm + wr * 32 + mf * 16 + l16 * 4 + r;
                float d1 = fmaxf(SQ[row] + sqc0 - 2.f * acc1[mf][nf][r], 0.f);
                float d2 = fmaxf(SQ[NN + row] + sqc1 - 2.f * acc2[mf][nf][r], 0.f);
                float t = __expf(-d1 * ia4);
                float t2 = t * t;
                float w = t + t2 + t2 * t2;
                float u = __expf(-d2 * ib4);
                float u2 = u * u;
                float g = u + u2 + u2 * u2;
                float val = ((1.f - eps) * w + eps) * g;
                val = (mk[row] && mcol) ? val : 0.f;
                S[(size_t)row * NN + col] = f2us(val);
            }
        }
    }
}

// ---------------- bandwidth, closed form (z = 0..5) ----------------
__global__ __launch_bounds__(256) void bw_fast6(const float* __restrict__ SQ6,
                                                const float* __restrict__ bnb,
                                                float* __restrict__ SCbw) {
    __shared__ float red[8];
    int z = blockIdx.x, tid = threadIdx.x;
    float s1p = 0.f;
    for (int r = tid; r < NN; r += 256) s1p += SQ6[z * NN + r];
    float b = bnb[tid];
    float s1 = block_reduce_sum256(s1p, red);
    float b2 = block_reduce_sum256(b * b, red);
    if (tid == 0)
        SCbw[z] = 2.f * (float)NN * s1 - 2.f * (float)NN * (float)NN * b2;
}

// ---------------- split-K finalize (bf16 slices) ----------------
template <int Z, bool RELU>
__global__ __launch_bounds__(256) void slice_fin_b(const ushort4* __restrict__ SL,
                                                   const float* __restrict__ bias,
                                                   __hip_bfloat16* __restrict__ out,
                                                   int N, size_t MN) {
    size_t v = (size_t)blockIdx.x * 256 + threadIdx.x;
    size_t MN4 = MN >> 2;
    float sx = 0.f, sy = 0.f, sz = 0.f, sw = 0.f;
#pragma unroll
    for (int z = 0; z < Z; ++z) {
        ushort4 t = SL[(size_t)z * MN4 + v];
        sx += us2f(t.x); sy += us2f(t.y); sz += us2f(t.z); sw += us2f(t.w);
    }
    float4 bb = ((const float4*)bias)[v % (size_t)(N >> 2)];
    sx += bb.x; sy += bb.y; sz += bb.z; sw += bb.w;
    if (RELU) {
        sx = fmaxf(sx, 0.f); sy = fmaxf(sy, 0.f);
        sz = fmaxf(sz, 0.f); sw = fmaxf(sw, 0.f);
    }
    union { __hip_bfloat16 h[4]; ushort4 u; } pk;
    pk.h[0] = f2bf(sx); pk.h[1] = f2bf(sy);
    pk.h[2] = f2bf(sz); pk.h[3] = f2bf(sw);
    ((ushort4*)out)[v] = pk.u;
}

// ---------------- conversions ----------------
__global__ void cvt_flat(const float* __restrict__ in, __hip_bfloat16* __restrict__ out,
                         int n4) {
    int i = blockIdx.x * 256 + threadIdx.x;
    if (i < n4) {
        float4 v = ((const float4*)in)[i];
        union { __hip_bfloat16 h[4]; ushort4 u; } pk;
        pk.h[0] = f2bf(v.x); pk.h[1] = f2bf(v.y);
        pk.h[2] = f2bf(v.z); pk.h[3] = f2bf(v.w);
        ((ushort4*)out)[i] = pk.u;
    }
}

// z-batched f32 [R,C] -> bf16 [C,R] (z slabs of R*C)
__global__ __launch_bounds__(256) void cvt_transz(const float* __restrict__ in,
                                                  __hip_bfloat16* __restrict__ out,
                                                  int R, int C) {
    __shared__ float t[32][33];
    size_t zo = (size_t)blockIdx.z * R * C;
    in += zo;
    out += zo;
    int bc = blockIdx.x * 32, br = blockIdx.y * 32;
    int tx = threadIdx.x & 31, ty = threadIdx.x >> 5;
#pragma unroll
    for (int i = 0; i < 32; i += 8)
        t[ty + i][tx] = in[(size_t)(br + ty + i) * C + bc + tx];
    __syncthreads();
#pragma unroll
    for (int i = 0; i < 32; i += 8)
        out[(size_t)(bc + ty + i) * R + br + tx] = f2bf(t[tx][ty + i]);
}

// ---------------- 3-plane (bf16) aggregation + threshold + cvt ------------
__global__ __launch_bounds__(256) void agg_cvt3(
    const ushort4* __restrict__ S3b, const int* __restrict__ mk0,
    const int* __restrict__ mk1, const int* __restrict__ mk2,
    const float* __restrict__ dissim, ushort4* __restrict__ Sb) {
    size_t v = (size_t)blockIdx.x * 256 + threadIdx.x;
    const size_t PL = (size_t)NN * NN / 4;
    int i = (int)(v >> 9);
    int j0 = (int)((v & 511) << 2);
    float thr = 1.f / (1.f + __expf(-dissim[0]));
    ushort4 u0 = S3b[v], u1 = S3b[PL + v], u2 = S3b[2 * PL + v];
    int m0i = mk0[i], m1i = mk1[i], m2i = mk2[i];
    union { __hip_bfloat16 h[4]; ushort4 u; } pk;
#define AGGC(C0, C1, C2, J)                                                       \
    {                                                                             \
        int j = j0 + J;                                                           \
        int cnt = ((m0i && mk0[j]) ? 1 : 0) + ((m1i && mk1[j]) ? 1 : 0) +         \
                  ((m2i && mk2[j]) ? 1 : 0);                                      \
        float a = cnt ? (us2f(C0) + us2f(C1) + us2f(C2)) / (float)cnt : 0.f;      \
        pk.h[J] = f2bf((a > thr) ? a : 0.f);                                      \
    }
    AGGC(u0.x, u1.x, u2.x, 0) AGGC(u0.y, u1.y, u2.y, 1)
    AGGC(u0.z, u1.z, u2.z, 2) AGGC(u0.w, u1.w, u2.w, 3)
#undef AGGC
    Sb[v] = pk.u;
}

// ---------------- BatchNorm column stats, z = modal*2 + {0:P(relu),1:E} ----
__global__ __launch_bounds__(256) void colstats6(const float* __restrict__ P3,
                                                 const float* __restrict__ E0,
                                                 const float* __restrict__ e1,
                                                 const float* __restrict__ e2,
                                                 float* __restrict__ mv, int nrows) {
    __shared__ float red[8];
    int c = blockIdx.x, z = blockIdx.y, tid = threadIdx.x;
    int m = z >> 1, kind = z & 1;
    const float* X = kind ? (m == 0 ? E0 : (m == 1 ? e1 : e2))
                          : P3 + (size_t)m * NN * DD;
    float s = 0.f, sq = 0.f;
    for (int r = tid; r < nrows; r += 256) {
        float v = X[(size_t)r * DD + c];
        if (!kind) v = fmaxf(v, 0.f);
        s += v; sq += v * v;
    }
    float ts = block_reduce_sum256(s, red);
    float tq = block_reduce_sum256(sq, red);
    if (tid == 0) {
        float mmean = ts / (float)nrows;
        mv[z * 512 + c] = mmean;
        mv[z * 512 + 256 + c] = tq / (float)nrows - mmean * mmean;
    }
}

// ---------------- fused BN-apply + rowsq, z = 0..5 (block = row) ----------
__global__ __launch_bounds__(256) void bn_fuse6(const float* __restrict__ P3,
                                                const float* __restrict__ E0,
                                                const float* __restrict__ e1,
                                                const float* __restrict__ e2,
                                                const float* __restrict__ mv,
                                                const float* __restrict__ g,
                                                const float* __restrict__ b,
                                                ushort* __restrict__ XB6,
                                                float* __restrict__ SQ6) {
    __shared__ float red[8];
    int r = blockIdx.x, z = blockIdx.y, c = threadIdx.x;
    int m = z >> 1, kind = z & 1;
    const float* X = kind ? (m == 0 ? E0 : (m == 1 ? e1 : e2))
                          : P3 + (size_t)m * NN * DD;
    float v = X[(size_t)r * DD + c];
    if (!kind) v = fmaxf(v, 0.f);
    float y = (v - mv[z * 512 + c]) * rsqrtf(mv[z * 512 + 256 + c] + 1e-5f) * g[c] + b[c];
    __hip_bfloat16 yb = f2bf(y);
    XB6[(size_t)z * NN * DD + (size_t)r * DD + c] = *(ushort*)&yb;
    float yr = bf2f(yb);
    float s = block_reduce_sum256(yr * yr, red);
    if (c == 0) SQ6[z * NN + r] = s;
}

// ---------------- z-batched sum-of-squares partial (z = modal) -------------
__global__ __launch_bounds__(256) void sumsq3(const float* __restrict__ X0,
                                              const float* __restrict__ X1,
                                              const float* __restrict__ X2,
                                              int n, float* __restrict__ part) {
    __shared__ float red[8];
    int z = blockIdx.y, tid = threadIdx.x;
    const float* X = (z == 0) ? X0 : ((z == 1) ? X1 : X2);
    float s = 0.f;
    for (size_t idx = (size_t)blockIdx.x * 256 + tid; idx < (size_t)n;
         idx += (size_t)gridDim.x * 256) {
        float v = X[idx];
        s += v * v;
    }
    float bs = block_reduce_sum256(s, red);
    if (tid == 0) part[512 + z * 512 + blockIdx.x] = bs;
}

// reduce6: blocks 0..2 -> |E|^2 (n=512) -> SC[9+b];
//          blocks 3..5 -> |P|^2 (n=64 thin-grid partials) -> SC[6+(b-3)]
__global__ __launch_bounds__(256) void reduce6(const float* __restrict__ part,
                                               float* __restrict__ SC) {
    __shared__ float red[8];
    int b = blockIdx.x, tid = threadIdx.x;
    const float* src; int n, dst;
    if (b < 3) { src = part + 512 + b * 512; n = 512; dst = 9 + b; }
    else { src = part + 2048 + (b - 3) * 64; n = 64; dst = 6 + (b - 3); }
    float s = 0.f;
    for (int i = tid; i < n; i += 256) s += src[i];
    float bs = block_reduce_sum256(s, red);
    if (tid == 0) SC[dst] = bs;
}

// ---------------- adapt-gate imputation ----------------
__global__ __launch_bounds__(256) void impute_k(
    const float* __restrict__ E, const __hip_bfloat16* __restrict__ H, int ldh,
    const float* __restrict__ aw, const float* __restrict__ ab,
    const int* __restrict__ mk, float* __restrict__ OUT) {
    __shared__ float red[8];
    int i = blockIdx.x, tid = threadIdx.x;
    float e = E[(size_t)i * DD + tid], h = bf2f(H[(size_t)i * ldh + tid]), w = aw[tid];
    float se = block_reduce_sum256(e * w, red);
    float sh = block_reduce_sum256(h * w, red);
    float s = 1.f / (1.f + __expf(-(se + ab[0])));
    float o = 1.f / (1.f + __expf(-(sh + ab[0])));
    s = s / (s + o);
    float imp = s * e + (1.f - s) * h;
    float m = mk[i] ? 1.f : 0.f;
    OUT[(size_t)i * DD + tid] = imp * m + (1.f - m) * h;
}

// ---------------- masks ----------------
__global__ void detect_mode(const void* __restrict__ m1, int* __restrict__ modep) {
    if (threadIdx.x == 0 && blockIdx.x == 0) {
        int vi = ((const int*)m1)[0];
        float vf = ((const float*)m1)[0];
        modep[0] = (vi == 1) ? 0 : ((vf == 1.0f) ? 2 : 1);
    }
}

__device__ __forceinline__ int rd_mask(const void* p, int idx, int mode) {
    if (mode == 0) return ((const int*)p)[idx] != 0;
    if (mode == 1) return ((const unsigned char*)p)[idx] != 0;
    return ((const float*)p)[idx] != 0.f;
}

__global__ void build_masks(const void* __restrict__ m0, const void* __restrict__ m1,
                            const void* __restrict__ m2, const int* __restrict__ modep,
                            int* __restrict__ MK, int* __restrict__ TOK) {
    int mode = modep[0];
    int idx = blockIdx.x * 256 + threadIdx.x;
    if (idx < NN) {
        MK[idx] = rd_mask(m0, idx * 32, mode);
        MK[NN + idx] = rd_mask(m1, idx, mode);
        MK[2 * NN + idx] = rd_mask(m2, idx, mode);
    }
    if (idx < NN * LTOK) {
        int i = idx / LTOK, t = idx - i * LTOK;
        TOK[idx] = (t < 32) ? rd_mask(m0, i * 32 + t, mode)
                            : ((t == 32) ? rd_mask(m1, i, mode) : rd_mask(m2, i, mode));
    }
}

// ---------------- gather emb0[:,0,:] ----------------
__global__ void gather_e0(const float* __restrict__ emb0, float* __restrict__ E0,
                          __hip_bfloat16* __restrict__ E0b) {
    int i = blockIdx.x, c = threadIdx.x;
    float v = emb0[(size_t)i * 32 * DD + c];
    E0[(size_t)i * DD + c] = v;
    E0b[(size_t)i * DD + c] = f2bf(v);
}

// ---------------- PE + type_emb[0] table ----------------
__global__ void pe_table(const float* __restrict__ type_emb, float* __restrict__ PET) {
    int t = blockIdx.x, c = threadIdx.x;
    float div = __expf((float)((c >> 1) << 1) * (-9.210340371976184f / 256.f));
    float ang = (float)t * div;
    float pe = (c & 1) ? __cosf(ang) : __sinf(ang);
    PET[t * 256 + c] = type_emb[c] + pe;
}

// ---------------- build token sequence ----------------
__global__ void build_z2(const float4* __restrict__ emb0, const float4* __restrict__ i0,
                         const float4* __restrict__ i1, const float4* __restrict__ i2,
                         const float4* __restrict__ PET,
                         const float4* __restrict__ type_emb,
                         ushort4* __restrict__ Z) {
    int idx = blockIdx.x * 256 + threadIdx.x;
    int c4 = idx & 63;
    int t = (idx >> 6) % LTOK;
    int i = idx / (LTOK * 64);
    float4 v, a;
    if (t < 32) {
        v = (t == 0) ? i0[(size_t)i * 64 + c4]
                     : emb0[((size_t)i * 32 + t) * 64 + c4];
        a = PET[t * 64 + c4];
    } else if (t == 32) {
        v = i1[(size_t)i * 64 + c4];
        a = type_emb[64 + c4];
    } else {
        v = i2[(size_t)i * 64 + c4];
        a = type_emb[128 + c4];
    }
    union { __hip_bfloat16 h[4]; ushort4 u; } pk;
    pk.h[0] = f2bf(v.x + a.x); pk.h[1] = f2bf(v.y + a.y);
    pk.h[2] = f2bf(v.z + a.z); pk.h[3] = f2bf(v.w + a.w);
    Z[idx] = pk.u;
}

// ---------------------------------------------------------------------------
// MFMA attention with in-LDS V-transpose. 1 sample/block, 4 waves.
// QKV row-major [rows][768] (Q|K|V). V is staged to VT_lds[256][42]
// (stride 42 = 21 dwords, gcd(21,32)=1 -> conflict-free both ways);
// j in [34,42) zeroed so cross-row bf16x8 reads multiply P-zeros.
// ---------------------------------------------------------------------------
template <int DH, int NH>
__global__ __launch_bounds__(256) void attn_mfma(
    const ushort* __restrict__ QKV, const int* __restrict__ tok,
    __hip_bfloat16* __restrict__ O, int sample0)
{
    __shared__ float S_lds[48][49];
    __shared__ ushort P_lds[48][72];
    __shared__ __align__(16) ushort VT_lds[256 * 42 + 64];
    __shared__ int tok_lds[34];
    const int s = blockIdx.x;
    const int tid = threadIdx.x;
    const int wv = tid >> 6, l = tid & 63, lr = l & 15, l16 = l >> 4;
    const int rowQ = s * 34;
    if (tid < 34) tok_lds[tid] = tok[(size_t)(sample0 + s) * LTOK + tid];
    for (int idx = tid; idx < 256 * 8 + 64; idx += 256) {
        int d = idx >> 3, jp = 34 + (idx & 7);
        int off = (idx < 2048) ? d * 42 + jp : 256 * 42 + (idx - 2048);
        VT_lds[off] = 0;
    }
    for (int idx = tid; idx < 34 * 256; idx += 256) {
        int j = idx >> 8, d = idx & 255;
        VT_lds[d * 42 + j] = QKV[(size_t)(rowQ + j) * 768 + 512 + d];
    }
    const float scale = rsqrtf((float)DH);
    __syncthreads();
#pragma unroll
    for (int h = 0; h < NH; ++h) {
        for (int t = wv; t < 9; t += 4) {
            int mj = t / 3, ni = t % 3;
            f32x4 acc = {0.f, 0.f, 0.f, 0.f};
#pragma unroll
            for (int ks = 0; ks < DH / 32; ++ks) {
                bf16x8 a = *(const bf16x8*)(QKV +
                    (size_t)(rowQ + mj * 16 + lr) * 768 + 256 + h * DH + ks * 32 + l16 * 8);
                bf16x8 b = *(const bf16x8*)(QKV +
                    (size_t)(rowQ + ni * 16 + lr) * 768 + h * DH + ks * 32 + l16 * 8);
                acc = __builtin_amdgcn_mfma_f32_16x16x32_bf16(a, b, acc, 0, 0, 0);
            }
#pragma unroll
            for (int r = 0; r < 4; ++r)
                S_lds[mj * 16 + l16 * 4 + r][ni * 16 + lr] = acc[r];
        }
        __syncthreads();
        if (tid < 48) {
            int i = tid;
            if (i < 34) {
                int ti = tok_lds[i];
                float sc[34];
                float mx = -1e30f;
#pragma unroll
                for (int j = 0; j < 34; ++j) {
                    float v = (ti && tok_lds[j]) ? S_lds[j][i] * scale : -1e9f;
                    sc[j] = v;
                    mx = fmaxf(mx, v);
                }
                float sum = 0.f;
#pragma unroll
                for (int j = 0; j < 34; ++j) {
                    sc[j] = __expf(sc[j] - mx);
                    sum += sc[j];
                }
                float inv = 1.f / sum;
#pragma unroll
                for (int j = 0; j < 34; ++j) P_lds[i][j] = f2us(sc[j] * inv);
#pragma unroll
                for (int j = 34; j < 64; ++j) P_lds[i][j] = 0;
            } else {
#pragma unroll
                for (int j = 0; j < 64; ++j) P_lds[i][j] = 0;
            }
        }
        __syncthreads();
        for (int nt = wv; nt < DH / 16; nt += 4) {
            f32x4 acc[3];
#pragma unroll
            for (int mi = 0; mi < 3; ++mi) acc[mi] = (f32x4){0.f, 0.f, 0.f, 0.f};
#pragma unroll
            for (int ks = 0; ks < 2; ++ks) {
                int j0 = ks * 32 + l16 * 8;
                int d = h * DH + nt * 16 + lr;
                bf16x8 bv;
                __builtin_memcpy(&bv, VT_lds + d * 42 + j0, 16);
#pragma unroll
                for (int mi = 0; mi < 3; ++mi) {
                    bf16x8 av = *(const bf16x8*)(&P_lds[0][0] + (mi * 16 + lr) * 72 + j0);
                    acc[mi] = __builtin_amdgcn_mfma_f32_16x16x32_bf16(av, bv, acc[mi], 0, 0, 0);
                }
            }
#pragma unroll
            for (int mi = 0; mi < 3; ++mi)
#pragma unroll
                for (int r = 0; r < 4; ++r) {
                    int i = mi * 16 + l16 * 4 + r;
                    if (i < 34)
                        O[(size_t)(rowQ + i) * 256 + h * DH + nt * 16 + lr] =
                            f2bf(acc[mi][r]);
                }
        }
        __syncthreads();
    }
}

// ---------------- wave-per-row LayerNorm ----------------
template <bool RELU>
__global__ __launch_bounds__(256) void ln_rows(__hip_bfloat16* __restrict__ Z,
                                               const float* __restrict__ g,
                                               const float* __restrict__ b) {
    int row = (blockIdx.x << 2) + (threadIdx.x >> 6);
    int l = threadIdx.x & 63;
    ushort4 u = ((ushort4*)(Z + (size_t)row * DD))[l];
    float x0 = us2f(u.x), x1 = us2f(u.y), x2 = us2f(u.z), x3 = us2f(u.w);
    float s = x0 + x1 + x2 + x3;
    for (int o = 1; o < 64; o <<= 1) s += __shfl_xor(s, o, 64);
    float mean = s * (1.f / 256.f);
    float d0 = x0 - mean, d1 = x1 - mean, d2 = x2 - mean, d3 = x3 - mean;
    float q = d0 * d0 + d1 * d1 + d2 * d2 + d3 * d3;
    for (int o = 1; o < 64; o <<= 1) q += __shfl_xor(q, o, 64);
    float rst = rsqrtf(q * (1.f / 256.f) + 1e-5f);
    float4 gg = ((const float4*)g)[l], bb = ((const float4*)b)[l];
    float y0 = d0 * rst * gg.x + bb.x, y1 = d1 * rst * gg.y + bb.y;
    float y2 = d2 * rst * gg.z + bb.z, y3 = d3 * rst * gg.w + bb.w;
    if (RELU) {
        y0 = fmaxf(y0, 0.f); y1 = fmaxf(y1, 0.f);
        y2 = fmaxf(y2, 0.f); y3 = fmaxf(y3, 0.f);
    }
    union { __hip_bfloat16 h[4]; ushort4 v; } pk;
    pk.h[0] = f2bf(y0); pk.h[1] = f2bf(y1); pk.h[2] = f2bf(y2); pk.h[3] = f2bf(y3);
    ((ushort4*)(Z + (size_t)row * DD))[l] = pk.v;
}

// ---------------- final head ----------------
__global__ __launch_bounds__(256) void head2(const __hip_bfloat16* __restrict__ Y1,
                                             const float* __restrict__ w,
                                             const float* __restrict__ b,
                                             float* __restrict__ out) {
    __shared__ float red[8];
    int i = blockIdx.x, tid = threadIdx.x;
    float s = bf2f(Y1[(size_t)i * 512 + tid]) * w[tid] +
              bf2f(Y1[(size_t)i * 512 + 256 + tid]) * w[256 + tid];
    float bs = block_reduce_sum256(s, red);
    if (tid == 0) out[i] = bs + b[0];
}

__global__ void lstab_k(const float* __restrict__ SC, float* __restrict__ dst) {
    if (threadIdx.x == 0 && blockIdx.x == 0) {
        float s = 0.f;
        for (int m = 0; m < 3; ++m)
            s += fabsf(sqrtf(SC[6 + m]) - sqrtf(SC[9 + m]));
        dst[0] = s;
    }
}

__global__ void gcn_bias_cat(const float* __restrict__ gcn_b, float* __restrict__ Bcat) {
    int m = blockIdx.x, l = blockIdx.y, c = threadIdx.x;
    Bcat[l * 768 + m * 256 + c] = gcn_b[(m * 2 + l) * 256 + c];
}

// ===========================================================================
#define GEMM(OUTM_, BIAS_, RELU_, A_, Bt_, BI_, C_, M_, N_, K_)                 \
    gemm_mfma<OUTM_, BIAS_, RELU_>                                              \
        <<<dim3((N_) / 128, (M_) / 128), 256, 0, stream>>>(                     \
            (const ushort*)(A_), (const ushort*)(Bt_), (BI_), (void*)(C_),      \
            (M_), (N_), (K_))
#define GEMMZ(A_, Bt_, C_, M_, N_, K_, Z_)                                      \
    gemm_mfma<5, false, false>                                                  \
        <<<dim3((N_) / 128, (M_) / 128, (Z_)), 256, 0, stream>>>(               \
            (const ushort*)(A_), (const ushort*)(Bt_), (const float*)nullptr,   \
            (void*)(C_), (M_), (N_), (K_))
#define GEMMT(OUTM_, BIAS_, RELU_, A_, Bt_, BI_, C_, M_, N_, K_)                \
    gemm_thin<OUTM_, BIAS_, RELU_>                                              \
        <<<dim3((N_) / 128, (M_) / 64), 256, 0, stream>>>(                      \
            (const ushort*)(A_), (const ushort*)(Bt_), (BI_), (void*)(C_),      \
            (M_), (N_), (K_))

extern "C" void kernel_launch(void* const* d_in, const int* in_sizes, int n_in,
                              void* d_out, int out_size, void* d_ws, size_t ws_size,
                              hipStream_t stream) {
    (void)in_sizes; (void)n_in; (void)out_size; (void)ws_size;
    const float* emb0 = (const float*)d_in[0];
    const float* emb1 = (const float*)d_in[1];
    const float* emb2 = (const float*)d_in[2];
    const void* msk0 = d_in[3];
    const void* msk1 = d_in[4];
    const void* msk2 = d_in[5];
    const float* simi_w = (const float*)d_in[6];
    const float* simi_b = (const float*)d_in[7];
    const float* bn_g = (const float*)d_in[8];
    const float* bn_b = (const float*)d_in[9];
    const float* simi_eps = (const float*)d_in[10];
    const float* dissim = (const float*)d_in[11];
    const float* gcn_w = (const float*)d_in[12];
    const float* gcn_b = (const float*)d_in[13];
    const float* adapt_w = (const float*)d_in[14];
    const float* adapt_b = (const float*)d_in[15];
    const float* type_emb = (const float*)d_in[16];
    const float* attn_w = (const float*)d_in[17];
    const float* attn_b = (const float*)d_in[18];
    const float* ffn_w1 = (const float*)d_in[19];
    const float* ffn_b1 = (const float*)d_in[20];
    const float* ffn_w2 = (const float*)d_in[21];
    const float* ffn_b2 = (const float*)d_in[22];
    const float* ln_g = (const float*)d_in[23];
    const float* ln_b = (const float*)d_in[24];
    const float* out_w1 = (const float*)d_in[25];
    const float* out_b1 = (const float*)d_in[26];
    const float* out_w2 = (const float*)d_in[27];
    const float* out_b2 = (const float*)d_in[28];
    float* out = (float*)d_out;

    const int ACH = 1024, ACROWS = ACH * LTOK;  // 34816 rows/chunk, 2 chunks

    // ---- workspace layout (~185 MB) ----
    char* wp = (char*)d_ws;
    auto alloc = [&](size_t bytes) -> char* {
        char* p = wp;
        wp += (bytes + 255) & ~(size_t)255;
        return p;
    };
    __hip_bfloat16* Zb = (__hip_bfloat16*)alloc((size_t)NN * LTOK * DD * 2);  // 35.7MB
    char* UN = alloc((size_t)80 * 1024 * 1024);  // union: S3b / QKVb|Ob / Hfb / SLICE
    ushort* S3b = (ushort*)UN;                                          // 25.2MB
    __hip_bfloat16* QKVb = (__hip_bfloat16*)UN;                         // 53.5MB
    __hip_bfloat16* Ob = (__hip_bfloat16*)(UN + (size_t)ACROWS * 768 * 2);  // 17.8MB
    __hip_bfloat16* Hfb = (__hip_bfloat16*)UN;
    __hip_bfloat16* SLICEB = (__hip_bfloat16*)UN;   // bf16 split-K slices
    __hip_bfloat16* Sb = (__hip_bfloat16*)alloc((size_t)NN * NN * 2);
    float* P3 = (float*)alloc((size_t)3 * NN * DD * 4);
    float* E0 = (float*)alloc((size_t)NN * DD * 4);
    __hip_bfloat16* Eb3 = (__hip_bfloat16*)alloc((size_t)3 * NN * DD * 2);
    __hip_bfloat16* T1b3 = (__hip_bfloat16*)alloc((size_t)3 * NN * DD * 2);
    __hip_bfloat16* T2b3 = (__hip_bfloat16*)alloc((size_t)3 * NN * DD * 2);
    ushort* XB6 = (ushort*)alloc((size_t)6 * NN * DD * 2);
    __hip_bfloat16* TBt3 = (__hip_bfloat16*)alloc((size_t)3 * NN * DD * 2);
    __hip_bfloat16* HB3 = (__hip_bfloat16*)alloc((size_t)NN * 768 * 2);
    __hip_bfloat16* HB2_3 = (__hip_bfloat16*)alloc((size_t)NN * 768 * 2);
    float* I0 = (float*)alloc((size_t)NN * DD * 4);
    float* I1 = (float*)alloc((size_t)NN * DD * 4);
    float* I2 = (float*)alloc((size_t)NN * DD * 4);
    __hip_bfloat16* Y1b = (__hip_bfloat16*)alloc((size_t)NN * 512 * 2);
    __hip_bfloat16* simi_wt = (__hip_bfloat16*)alloc((size_t)9 * 65536 * 2);
    __hip_bfloat16* gcn_wt = (__hip_bfloat16*)alloc((size_t)6 * 65536 * 2);
    __hip_bfloat16* attn_wt = (__hip_bfloat16*)alloc((size_t)8 * 65536 * 2);
    __hip_bfloat16* w1t = (__hip_bfloat16*)alloc((size_t)2 * 262144 * 2);
    __hip_bfloat16* w2t = (__hip_bfloat16*)alloc((size_t)2 * 262144 * 2);
    __hip_bfloat16* ow1t = (__hip_bfloat16*)alloc((size_t)8704 * 512 * 2);
    float* PET = (float*)alloc(32 * 256 * 4);
    float* MV6 = (float*)alloc(6 * 512 * 4);
    float* SQ6 = (float*)alloc(6 * NN * 4);
    float* PART = (float*)alloc(4096 * 4);  // [512:2048) E, [2048:2240) P (64/modal)
    float* SC = (float*)alloc(64 * 4);   // 6..8 |P|^2, 9..11 |E|^2, 16 mode, 20..25 bw
    float* Bcat = (float*)alloc(1536 * 4);
    int* TOK = (int*)alloc((size_t)NN * LTOK * 4);
    int* MK = (int*)alloc((size_t)3 * NN * 4);

    // ---- weight transpose-convert (z-batched: 6 launches) ----
    cvt_transz<<<dim3(8, 8, 9), 256, 0, stream>>>(simi_w, simi_wt, 256, 256);
    cvt_transz<<<dim3(8, 8, 6), 256, 0, stream>>>(gcn_w, gcn_wt, 256, 256);
    cvt_transz<<<dim3(8, 8, 8), 256, 0, stream>>>(attn_w, attn_wt, 256, 256);
    cvt_transz<<<dim3(32, 8, 2), 256, 0, stream>>>(ffn_w1, w1t, 256, 1024);
    cvt_transz<<<dim3(8, 32, 2), 256, 0, stream>>>(ffn_w2, w2t, 1024, 256);
    cvt_transz<<<dim3(16, 272, 1), 256, 0, stream>>>(out_w1, ow1t, 8704, 512);

    // ---- prep ----
    pe_table<<<32, 256, 0, stream>>>(type_emb, PET);
    gather_e0<<<NN, 256, 0, stream>>>(emb0, E0, Eb3);
    cvt_flat<<<512, 256, 0, stream>>>(emb1, Eb3 + (size_t)NN * DD, NN * DD / 4);
    cvt_flat<<<512, 256, 0, stream>>>(emb2, Eb3 + (size_t)2 * NN * DD, NN * DD / 4);
    detect_mode<<<1, 64, 0, stream>>>(msk1, (int*)SC + 16);
    build_masks<<<(NN * LTOK + 255) / 256, 256, 0, stream>>>(msk0, msk1, msk2,
                                                             (int*)SC + 16, MK, TOK);
    gcn_bias_cat<<<dim3(3, 2), 256, 0, stream>>>(gcn_b, Bcat);

    const float* Ef[3] = {E0, emb1, emb2};

    // ---- Stage A (thin z-batched MLP; |E|^2 z-batched) ----
    sumsq3<<<dim3(512, 3), 256, 0, stream>>>(E0, emb1, emb2, NN * DD, PART);
    gemm_batch_t<1, true, true, false><<<dim3(2, 32, 3), 256, 0, stream>>>(
        (const ushort*)Eb3, 256, (size_t)NN * DD, (const ushort*)simi_wt,
        (size_t)3 * 65536, simi_b, 3 * 256, T1b3, 256, (size_t)NN * DD,
        nullptr, NN, 256, 256);
    gemm_batch_t<1, true, true, false><<<dim3(2, 32, 3), 256, 0, stream>>>(
        (const ushort*)T1b3, 256, (size_t)NN * DD, (const ushort*)(simi_wt + 65536),
        (size_t)3 * 65536, simi_b + 256, 3 * 256, T2b3, 256, (size_t)NN * DD,
        nullptr, NN, 256, 256);
    gemm_batch_t<0, false, true, true><<<dim3(2, 32, 3), 256, 0, stream>>>(
        (const ushort*)T2b3, 256, (size_t)NN * DD, (const ushort*)(simi_wt + 2 * 65536),
        (size_t)3 * 65536, simi_b + 2 * 256, 3 * 256, P3, 256, (size_t)NN * DD,
        PART + 2048, NN, 256, 256);
    reduce6<<<6, 256, 0, stream>>>(PART, SC);

    colstats6<<<dim3(256, 6), 256, 0, stream>>>(P3, E0, emb1, emb2, MV6, NN);
    bn_fuse6<<<dim3(NN, 6), 256, 0, stream>>>(P3, E0, emb1, emb2, MV6, bn_g, bn_b,
                                              XB6, SQ6);
    bw_fast6<<<6, 256, 0, stream>>>(SQ6, bn_b, SC + 20);

    // z=3 parallel masked GK planes into S3b (bf16, thin tile, UN region)
    gemm_dist_gk3<<<dim3(16, 32, 3), 256, 0, stream>>>(XB6, SQ6, SC + 20, MK,
                                                       simi_eps, S3b);

    // ---- Stage B (bf16 split-K slices; thin GCN weight GEMMs) ----
    agg_cvt3<<<4096, 256, 0, stream>>>((const ushort4*)S3b, MK, MK + NN, MK + 2 * NN,
                                       dissim, (ushort4*)Sb);
    gemm_batch_t<2, false, false, false><<<dim3(2, 32, 3), 256, 0, stream>>>(
        (const ushort*)Eb3, 256, (size_t)NN * DD, (const ushort*)gcn_wt,
        (size_t)2 * 65536, nullptr, 0, TBt3, 256, (size_t)NN * DD,
        nullptr, NN, 256, 256);
    GEMMZ(Sb, TBt3, SLICEB, NN, 768, NN, 8);
    slice_fin_b<8, true><<<1536, 256, 0, stream>>>((const ushort4*)SLICEB, Bcat, HB3,
                                                   768, (size_t)NN * 768);
    gemm_batch_t<2, false, false, false><<<dim3(2, 32, 3), 256, 0, stream>>>(
        (const ushort*)HB3, 768, (size_t)256, (const ushort*)(gcn_wt + 65536),
        (size_t)2 * 65536, nullptr, 0, TBt3, 256, (size_t)NN * DD,
        nullptr, NN, 256, 256);
    GEMMZ(Sb, TBt3, SLICEB, NN, 768, NN, 8);
    slice_fin_b<8, true><<<1536, 256, 0, stream>>>((const ushort4*)SLICEB, Bcat + 768,
                                                   HB2_3, 768, (size_t)NN * 768);
    float* IMP[3] = {I0, I1, I2};
    for (int m = 0; m < 3; ++m)
        impute_k<<<NN, 256, 0, stream>>>(Ef[m], HB2_3 + m * 256, 768,
                                         adapt_w + m * 256, adapt_b + m,
                                         MK + m * NN, IMP[m]);

    // ---- Stage C: 34-token transformer (2 chunks of 1024 samples) ----
    build_z2<<<NN * LTOK * 64 / 256, 256, 0, stream>>>(
        (const float4*)emb0, (const float4*)I0, (const float4*)I1, (const float4*)I2,
        (const float4*)PET, (const float4*)type_emb, (ushort4*)Zb);
    const int NCHUNK = NN / ACH;  // 2
    for (int li = 0; li < 2; ++li) {
        for (int c = 0; c < NCHUNK; ++c) {
            __hip_bfloat16* Zc = Zb + (size_t)c * ACROWS * DD;
            GEMMT(1, true, false, Zc, attn_wt + (size_t)(li * 4) * 65536,
                  attn_b + li * 4 * 256, QKVb, ACROWS, 768, 256);
            if (li == 0)
                attn_mfma<64, 4><<<ACH, 256, 0, stream>>>(
                    (const ushort*)QKVb, TOK, Ob, c * ACH);
            else
                attn_mfma<256, 1><<<ACH, 256, 0, stream>>>(
                    (const ushort*)QKVb, TOK, Ob, c * ACH);
            GEMMT(3, true, false, Ob, attn_wt + (size_t)(li * 4 + 3) * 65536,
                  attn_b + (li * 4 + 3) * 256, Zc, ACROWS, 256, 256);
        }
        ln_rows<false><<<NN * LTOK / 4, 256, 0, stream>>>(Zb, ln_g + (li * 2 + 0) * 256,
                                                          ln_b + (li * 2 + 0) * 256);
        for (int c = 0; c < NCHUNK; ++c) {
            __hip_bfloat16* Zc = Zb + (size_t)c * ACROWS * DD;
            GEMM(1, true, true, Zc, w1t + (size_t)li * 262144, ffn_b1 + li * 1024,
                 Hfb, ACROWS, 1024, 256);
            GEMMT(3, true, false, Hfb, w2t + (size_t)li * 262144, ffn_b2 + li * 256,
                  Zc, ACROWS, 256, 1024);
        }
        ln_rows<true><<<NN * LTOK / 4, 256, 0, stream>>>(Zb, ln_g + (li * 2 + 1) * 256,
                                                         ln_b + (li * 2 + 1) * 256);
    }

    // ---- head (bf16 split-K Z=8, SLICEB in UN which is now free) ----
    GEMMZ(Zb, ow1t, SLICEB, NN, 512, LTOK * DD, 8);
    slice_fin_b<8, true><<<1024, 256, 0, stream>>>((const ushort4*)SLICEB, out_b1, Y1b,
                                                   512, (size_t)NN * 512);
    head2<<<NN, 256, 0, stream>>>(Y1b, out_w2, out_b2, out);
    lstab_k<<<1, 64, 0, stream>>>(SC, out + NN);
}